// Round 1
// baseline (8437.816 us; speedup 1.0000x reference)
//
#include <hip/hip_runtime.h>
#include <math.h>

// Problem constants (PCUTransformer)
#define B_    8
#define L_    1000
#define F_    7
#define DM_   512
#define H_    8
#define DFF_  2048
#define NL_   4
#define PRED_ 50
#define DK_   64
#define P_    16
#define EPS_  1e-5f
#define SCALE_ 0.125f   // 1/sqrt(64)

// ---------------- wave reduction helpers ----------------
__device__ inline float wave_reduce_sum(float x) {
#pragma unroll
  for (int off = 32; off >= 1; off >>= 1) x += __shfl_xor(x, off, 64);
  return x;
}
__device__ inline float wave_reduce_max(float x) {
#pragma unroll
  for (int off = 32; off >= 1; off >>= 1) x = fmaxf(x, __shfl_xor(x, off, 64));
  return x;
}

// ---------------- embedding: h = x @ emb_w + emb_b + pe ----------------
// grid = B*L blocks, block = DM threads
__global__ __launch_bounds__(512)
void embed_kernel(const float* __restrict__ x, const float* __restrict__ emb_w,
                  const float* __restrict__ emb_b, const float* __restrict__ pe,
                  float* __restrict__ h) {
  int bl = blockIdx.x;            // 0..7999
  int l = bl % L_;
  int d = threadIdx.x;
  const float* xr = x + (size_t)bl * F_;
  float acc = emb_b[d] + pe[(size_t)l * DM_ + d];
#pragma unroll
  for (int f = 0; f < F_; f++) acc = fmaf(xr[f], emb_w[f * DM_ + d], acc);
  h[(size_t)bl * DM_ + d] = acc;
}

// ---------------- generic fp32 GEMM: C = A[M,K] @ W[K,N] + bias (+resid) (relu?) ----
// BM=BN=128, BK=16, 256 threads, 8x8 per thread.
__global__ __launch_bounds__(256)
void gemm_kernel(const float* __restrict__ A, const float* __restrict__ W,
                 const float* __restrict__ bias, const float* __restrict__ resid,
                 float* __restrict__ C, int M, int K, int N, int relu) {
  __shared__ float As[16][132];   // transposed A tile: As[k][m]
  __shared__ float Bs[16][132];   // Bs[k][n]
  int m0 = blockIdx.y * 128;
  int n0 = blockIdx.x * 128;
  int t = threadIdx.x;
  int tx = t & 15, ty = t >> 4;

  float acc[8][8];
#pragma unroll
  for (int i = 0; i < 8; i++)
#pragma unroll
    for (int j = 0; j < 8; j++) acc[i][j] = 0.f;

  int a_row = t >> 1, a_col = (t & 1) * 8;     // 128 rows x 16 k, 8 floats/thread
  int b_row = t >> 4, b_col = (t & 15) * 8;    // 16 k x 128 n, 8 floats/thread
  int a_m = m0 + a_row; if (a_m > M - 1) a_m = M - 1;   // clamp (stores guarded)
  const float* Ap = A + (size_t)a_m * K + a_col;
  const float* Wp = W + (size_t)b_row * N + n0 + b_col;

  for (int k0 = 0; k0 < K; k0 += 16) {
    float4 av0 = *(const float4*)(Ap + k0);
    float4 av1 = *(const float4*)(Ap + k0 + 4);
    float4 bv0 = *(const float4*)(Wp + (size_t)k0 * N);
    float4 bv1 = *(const float4*)(Wp + (size_t)k0 * N + 4);
    __syncthreads();
    As[a_col + 0][a_row] = av0.x;
    As[a_col + 1][a_row] = av0.y;
    As[a_col + 2][a_row] = av0.z;
    As[a_col + 3][a_row] = av0.w;
    As[a_col + 4][a_row] = av1.x;
    As[a_col + 5][a_row] = av1.y;
    As[a_col + 6][a_row] = av1.z;
    As[a_col + 7][a_row] = av1.w;
    *(float4*)&Bs[b_row][b_col]     = bv0;
    *(float4*)&Bs[b_row][b_col + 4] = bv1;
    __syncthreads();
#pragma unroll
    for (int kk = 0; kk < 16; kk++) {
      float a[8], b[8];
      ((float4*)a)[0] = *(const float4*)&As[kk][ty * 8];
      ((float4*)a)[1] = *(const float4*)&As[kk][ty * 8 + 4];
      ((float4*)b)[0] = *(const float4*)&Bs[kk][tx * 8];
      ((float4*)b)[1] = *(const float4*)&Bs[kk][tx * 8 + 4];
#pragma unroll
      for (int i = 0; i < 8; i++)
#pragma unroll
        for (int j = 0; j < 8; j++) acc[i][j] = fmaf(a[i], b[j], acc[i][j]);
    }
  }

#pragma unroll
  for (int i = 0; i < 8; i++) {
    int m = m0 + ty * 8 + i;
    if (m >= M) continue;
    size_t crow = (size_t)m * N;
#pragma unroll
    for (int jj = 0; jj < 2; jj++) {
      int n = n0 + tx * 8 + jj * 4;
      float4 r;
      r.x = acc[i][jj * 4 + 0] + bias[n + 0];
      r.y = acc[i][jj * 4 + 1] + bias[n + 1];
      r.z = acc[i][jj * 4 + 2] + bias[n + 2];
      r.w = acc[i][jj * 4 + 3] + bias[n + 3];
      if (resid) {
        const float4 rv = *(const float4*)&resid[crow + n];
        r.x += rv.x; r.y += rv.y; r.z += rv.z; r.w += rv.w;
      }
      if (relu) {
        r.x = fmaxf(r.x, 0.f); r.y = fmaxf(r.y, 0.f);
        r.z = fmaxf(r.z, 0.f); r.w = fmaxf(r.w, 0.f);
      }
      *(float4*)&C[crow + n] = r;
    }
  }
}

// ---------------- learned-mask projection: dst[b,l,h,p] = src_head_row . w + bias ----
// grid = B*L, block = 128 (h = t>>4, p = t&15)
__global__ __launch_bounds__(128)
void lmproj_kernel(const float* __restrict__ src, const float* __restrict__ w,
                   const float* __restrict__ bias, float* __restrict__ dst) {
  int bl = blockIdx.x;
  int t = threadIdx.x;
  int hh = t >> 4, p = t & 15;
  const float* s = src + (size_t)bl * DM_ + hh * DK_;
  float acc = bias[p];
#pragma unroll
  for (int d = 0; d < DK_; d++) acc = fmaf(s[d], w[d * P_ + p], acc);
  dst[((size_t)bl * H_ + hh) * P_ + p] = acc;
}

// ---------------- attention with learned-mask tanh bias, online softmax ----------
// grid = (L/4, B*H), block = 256 (4 waves; one wave per query row; lane = out dim)
__global__ __launch_bounds__(256)
void attn_kernel(const float* __restrict__ q, const float* __restrict__ k,
                 const float* __restrict__ v, const float* __restrict__ qp,
                 const float* __restrict__ kp, float* __restrict__ ctx) {
  __shared__ float Ks[64][68];
  __shared__ float Vs[64][68];
  __shared__ float kps[64][16];
  __shared__ float ps[4][64];
  int bh = blockIdx.y;
  int b = bh >> 3, hh = bh & 7;
  int t = threadIdx.x;
  int wv = t >> 6, lane = t & 63;
  int l = blockIdx.x * 4 + wv;

  const float* qrow = q + (size_t)(b * L_ + l) * DM_ + hh * DK_;
  float4 qv[16];
#pragma unroll
  for (int i = 0; i < 16; i++) {
    float4 tv = *(const float4*)(qrow + i * 4);
    qv[i] = make_float4(tv.x * SCALE_, tv.y * SCALE_, tv.z * SCALE_, tv.w * SCALE_);
  }
  const float* qprow = qp + ((size_t)(b * L_ + l) * H_ + hh) * P_;
  float4 qpv[4];
#pragma unroll
  for (int i = 0; i < 4; i++) qpv[i] = *(const float4*)(qprow + i * 4);

  float mrun = -1e30f, lrun = 0.f, acc = 0.f;
  int srow = t >> 2, part = t & 3;

  for (int s0 = 0; s0 < L_; s0 += 64) {
    int sg = s0 + srow; if (sg > L_ - 1) sg = L_ - 1;   // clamp; OOB masked below
    const float* krow = k + (size_t)(b * L_ + sg) * DM_ + hh * DK_ + part * 16;
    const float* vrow = v + (size_t)(b * L_ + sg) * DM_ + hh * DK_ + part * 16;
    float4 kv0 = *(const float4*)(krow + 0);
    float4 kv1 = *(const float4*)(krow + 4);
    float4 kv2 = *(const float4*)(krow + 8);
    float4 kv3 = *(const float4*)(krow + 12);
    float4 vv0 = *(const float4*)(vrow + 0);
    float4 vv1 = *(const float4*)(vrow + 4);
    float4 vv2 = *(const float4*)(vrow + 8);
    float4 vv3 = *(const float4*)(vrow + 12);
    float4 kpv = *(const float4*)(kp + ((size_t)(b * L_ + sg) * H_ + hh) * P_ + part * 4);
    __syncthreads();   // all waves finished with previous tile
    *(float4*)&Ks[srow][part * 16 + 0]  = kv0;
    *(float4*)&Ks[srow][part * 16 + 4]  = kv1;
    *(float4*)&Ks[srow][part * 16 + 8]  = kv2;
    *(float4*)&Ks[srow][part * 16 + 12] = kv3;
    *(float4*)&Vs[srow][part * 16 + 0]  = vv0;
    *(float4*)&Vs[srow][part * 16 + 4]  = vv1;
    *(float4*)&Vs[srow][part * 16 + 8]  = vv2;
    *(float4*)&Vs[srow][part * 16 + 12] = vv3;
    *(float4*)&kps[srow][part * 4] = kpv;
    __syncthreads();   // tiles staged

    int s = s0 + lane;
    float dot = 0.f, md = 0.f;
#pragma unroll
    for (int i = 0; i < 16; i++) {
      float4 kk4 = *(const float4*)&Ks[lane][i * 4];
      dot = fmaf(qv[i].x, kk4.x, dot);
      dot = fmaf(qv[i].y, kk4.y, dot);
      dot = fmaf(qv[i].z, kk4.z, dot);
      dot = fmaf(qv[i].w, kk4.w, dot);
    }
#pragma unroll
    for (int i = 0; i < 4; i++) {
      float4 kp4 = *(const float4*)&kps[lane][i * 4];
      md = fmaf(qpv[i].x, kp4.x, md);
      md = fmaf(qpv[i].y, kp4.y, md);
      md = fmaf(qpv[i].z, kp4.z, md);
      md = fmaf(qpv[i].w, kp4.w, md);
    }
    float score = dot + tanhf(md);
    if (s >= L_) score = -1e30f;

    float tm = wave_reduce_max(score);
    float mnew = fmaxf(mrun, tm);
    float p = (s < L_) ? __expf(score - mnew) : 0.f;
    float alpha = __expf(mrun - mnew);           // first tile: exp(-1e30) = 0
    float psum = wave_reduce_sum(p);
    lrun = lrun * alpha + psum;
    ps[wv][lane] = p;
    __syncthreads();   // make ps visible (block-wide barrier is simplest safe choice)
    acc *= alpha;
#pragma unroll 8
    for (int ss = 0; ss < 64; ss++) acc = fmaf(ps[wv][ss], Vs[ss][lane], acc);
    mrun = mnew;
  }
  ctx[(size_t)(b * L_ + l) * DM_ + hh * DK_ + lane] = acc / lrun;
}

// ---------------- layernorm: out = LN(a (+ badd)) * g + be, row length DM ------
// grid = rows, block = 256 (each thread handles 2 elements)
__global__ __launch_bounds__(256)
void ln_kernel(const float* __restrict__ a, const float* __restrict__ badd,
               const float* __restrict__ g, const float* __restrict__ be,
               float* __restrict__ o) {
  int row = blockIdx.x;
  int t = threadIdx.x;
  size_t base = (size_t)row * DM_;
  float x0 = a[base + t], x1 = a[base + t + 256];
  if (badd) { x0 += badd[base + t]; x1 += badd[base + t + 256]; }
  float s = x0 + x1;
  float ss = x0 * x0 + x1 * x1;
  s = wave_reduce_sum(s);
  ss = wave_reduce_sum(ss);
  __shared__ float sh_s[4], sh_ss[4];
  int wv = t >> 6, lane = t & 63;
  if (lane == 0) { sh_s[wv] = s; sh_ss[wv] = ss; }
  __syncthreads();
  float S = sh_s[0] + sh_s[1] + sh_s[2] + sh_s[3];
  float SS = sh_ss[0] + sh_ss[1] + sh_ss[2] + sh_ss[3];
  float mean = S * (1.0f / DM_);
  float var = SS * (1.0f / DM_) - mean * mean;
  float rstd = rsqrtf(var + EPS_);
  o[base + t]       = (x0 - mean) * rstd * g[t] + be[t];
  o[base + t + 256] = (x1 - mean) * rstd * g[t + 256] + be[t + 256];
}

// ---------------- final: LN(h[b,L-1,:]) @ fc_w + fc_b -> out[b, PRED] ----------
__global__ __launch_bounds__(512)
void final_kernel(const float* __restrict__ h, const float* __restrict__ gn,
                  const float* __restrict__ bn, const float* __restrict__ fcw,
                  const float* __restrict__ fcb, float* __restrict__ out) {
  int b = blockIdx.x;
  int t = threadIdx.x;
  size_t base = ((size_t)b * L_ + (L_ - 1)) * DM_;
  float x = h[base + t];
  float s = wave_reduce_sum(x);
  float ss = wave_reduce_sum(x * x);
  __shared__ float sh_s[8], sh_ss[8];
  int wv = t >> 6, lane = t & 63;
  if (lane == 0) { sh_s[wv] = s; sh_ss[wv] = ss; }
  __syncthreads();
  float S = 0.f, SS = 0.f;
#pragma unroll
  for (int i = 0; i < 8; i++) { S += sh_s[i]; SS += sh_ss[i]; }
  float mean = S * (1.0f / DM_);
  float var = SS * (1.0f / DM_) - mean * mean;
  float rstd = rsqrtf(var + EPS_);
  __shared__ float hn[DM_];
  hn[t] = (x - mean) * rstd * gn[t] + bn[t];
  __syncthreads();
  if (t < PRED_) {
    float acc = fcb[t];
#pragma unroll 8
    for (int d = 0; d < DM_; d++) acc = fmaf(hn[d], fcw[d * PRED_ + t], acc);
    out[b * PRED_ + t] = acc;
  }
}

// ---------------- driver ----------------
extern "C" void kernel_launch(void* const* d_in, const int* in_sizes, int n_in,
                              void* d_out, int out_size, void* d_ws, size_t ws_size,
                              hipStream_t stream) {
  const float* x     = (const float*)d_in[0];
  const float* emb_w = (const float*)d_in[1];
  const float* emb_b = (const float*)d_in[2];
  const float* pe    = (const float*)d_in[3];
  const float* Wq = (const float*)d_in[4];  const float* bq = (const float*)d_in[5];
  const float* Wk = (const float*)d_in[6];  const float* bk = (const float*)d_in[7];
  const float* Wv = (const float*)d_in[8];  const float* bv = (const float*)d_in[9];
  const float* Wo = (const float*)d_in[10]; const float* bo = (const float*)d_in[11];
  const float* W1 = (const float*)d_in[12]; const float* b1 = (const float*)d_in[13];
  const float* W2 = (const float*)d_in[14]; const float* b2 = (const float*)d_in[15];
  const float* g1 = (const float*)d_in[16]; const float* be1 = (const float*)d_in[17];
  const float* g2 = (const float*)d_in[18]; const float* be2 = (const float*)d_in[19];
  const float* lm_qw = (const float*)d_in[20]; const float* lm_qb = (const float*)d_in[21];
  const float* lm_kw = (const float*)d_in[22]; const float* lm_kb = (const float*)d_in[23];
  const float* gn = (const float*)d_in[24]; const float* bn = (const float*)d_in[25];
  const float* fc_w = (const float*)d_in[26]; const float* fc_b = (const float*)d_in[27];
  float* out = (float*)d_out;

  // workspace layout (floats): total 26.624M floats = 106.5 MB
  float* ws = (float*)d_ws;
  const size_t ROWS = (size_t)B_ * L_;          // 8000
  float* h    = ws;                              // [8000,512]
  float* q    = h   + ROWS * DM_;                // [8000,512]
  float* k    = q   + ROWS * DM_;
  float* v    = k   + ROWS * DM_;
  float* ctx  = v   + ROWS * DM_;
  float* t0   = ctx + ROWS * DM_;                // gemm-out / y buffer
  float* qp   = t0  + ROWS * DM_;                // [8000,8,16]
  float* kp   = qp  + ROWS * H_ * P_;
  float* ffn1 = q;   // [8000,2048] aliases q..ctx (dead during FFN)

  embed_kernel<<<dim3((unsigned)ROWS), 512, 0, stream>>>(x, emb_w, emb_b, pe, h);

  dim3 gqkv(DM_ / 128, (8000 + 127) / 128);      // (4, 63)
  dim3 gffn1(DFF_ / 128, (8000 + 127) / 128);    // (16, 63)
  dim3 gattn(L_ / 4, B_ * H_);                   // (250, 64)

  for (int i = 0; i < NL_; i++) {
    const float* Wq_i = Wq + (size_t)i * DM_ * DM_;
    const float* Wk_i = Wk + (size_t)i * DM_ * DM_;
    const float* Wv_i = Wv + (size_t)i * DM_ * DM_;
    const float* Wo_i = Wo + (size_t)i * DM_ * DM_;
    const float* W1_i = W1 + (size_t)i * DM_ * DFF_;
    const float* W2_i = W2 + (size_t)i * DFF_ * DM_;

    gemm_kernel<<<gqkv, 256, 0, stream>>>(h, Wq_i, bq + i * DM_, nullptr, q, 8000, DM_, DM_, 0);
    gemm_kernel<<<gqkv, 256, 0, stream>>>(h, Wk_i, bk + i * DM_, nullptr, k, 8000, DM_, DM_, 0);
    gemm_kernel<<<gqkv, 256, 0, stream>>>(h, Wv_i, bv + i * DM_, nullptr, v, 8000, DM_, DM_, 0);

    lmproj_kernel<<<dim3((unsigned)ROWS), 128, 0, stream>>>(q, lm_qw, lm_qb, qp);
    lmproj_kernel<<<dim3((unsigned)ROWS), 128, 0, stream>>>(k, lm_kw, lm_kb, kp);

    attn_kernel<<<gattn, 256, 0, stream>>>(q, k, v, qp, kp, ctx);

    // t0 = ctx @ Wo + bo + h ; h = LN(t0, g1, be1)
    gemm_kernel<<<gqkv, 256, 0, stream>>>(ctx, Wo_i, bo + i * DM_, h, t0, 8000, DM_, DM_, 0);
    ln_kernel<<<dim3((unsigned)ROWS), 256, 0, stream>>>(t0, nullptr, g1 + i * DM_, be1 + i * DM_, h);

    // ffn1 = relu(h @ W1 + b1) ; y(t0) = ffn1 @ W2 + b2
    gemm_kernel<<<gffn1, 256, 0, stream>>>(h, W1_i, b1 + i * DFF_, nullptr, ffn1, 8000, DM_, DFF_, 1);
    gemm_kernel<<<gqkv, 256, 0, stream>>>(ffn1, W2_i, b2 + i * DM_, nullptr, t0, 8000, DFF_, DM_, 0);

    // h2 = LN(h + y); h = LN(h2 + y)   (norm2 applied twice, same params)
    ln_kernel<<<dim3((unsigned)ROWS), 256, 0, stream>>>(h, t0, g2 + i * DM_, be2 + i * DM_, h);
    ln_kernel<<<dim3((unsigned)ROWS), 256, 0, stream>>>(h, t0, g2 + i * DM_, be2 + i * DM_, h);
  }

  final_kernel<<<B_, 512, 0, stream>>>(h, gn, bn, fc_w, fc_b, out);
}

// Round 2
// 3934.801 us; speedup vs baseline: 2.1444x; 2.1444x over previous
//
#include <hip/hip_runtime.h>
#include <math.h>

// Problem constants (PCUTransformer)
#define B_    8
#define L_    1000
#define F_    7
#define DM_   512
#define H_    8
#define DFF_  2048
#define NL_   4
#define PRED_ 50
#define DK_   64
#define P_    16
#define EPS_  1e-5f
#define SCALE_ 0.125f   // 1/sqrt(64)

typedef __bf16 bf16x8 __attribute__((ext_vector_type(8)));
typedef float  f32x4  __attribute__((ext_vector_type(4)));

// ---------------- helpers ----------------
__device__ inline float wave_reduce_sum(float x) {
#pragma unroll
  for (int off = 32; off >= 1; off >>= 1) x += __shfl_xor(x, off, 64);
  return x;
}

__device__ inline unsigned short f2bf(float f) {   // RNE float->bf16 bits
  unsigned int u = __float_as_uint(f);
  unsigned int r = u + 0x7FFFu + ((u >> 16) & 1u);
  return (unsigned short)(r >> 16);
}
__device__ inline unsigned int pack2(float a, float b) {
  return (unsigned int)f2bf(a) | ((unsigned int)f2bf(b) << 16);
}

union bfrag { bf16x8 b; unsigned short u[8]; uint4 q; };

// ---------------- embedding: h = x @ emb_w + emb_b + pe ----------------
__global__ __launch_bounds__(512)
void embed_kernel(const float* __restrict__ x, const float* __restrict__ emb_w,
                  const float* __restrict__ emb_b, const float* __restrict__ pe,
                  float* __restrict__ h) {
  int bl = blockIdx.x;
  int l = bl % L_;
  int d = threadIdx.x;
  const float* xr = x + (size_t)bl * F_;
  float acc = emb_b[d] + pe[(size_t)l * DM_ + d];
#pragma unroll
  for (int f = 0; f < F_; f++) acc = fmaf(xr[f], emb_w[f * DM_ + d], acc);
  h[(size_t)bl * DM_ + d] = acc;
}

// ---------------- generic fp32 GEMM (unchanged from R1) ----------------
__global__ __launch_bounds__(256)
void gemm_kernel(const float* __restrict__ A, const float* __restrict__ W,
                 const float* __restrict__ bias, const float* __restrict__ resid,
                 float* __restrict__ C, int M, int K, int N, int relu) {
  __shared__ float As[16][132];
  __shared__ float Bs[16][132];
  int m0 = blockIdx.y * 128;
  int n0 = blockIdx.x * 128;
  int t = threadIdx.x;
  int tx = t & 15, ty = t >> 4;

  float acc[8][8];
#pragma unroll
  for (int i = 0; i < 8; i++)
#pragma unroll
    for (int j = 0; j < 8; j++) acc[i][j] = 0.f;

  int a_row = t >> 1, a_col = (t & 1) * 8;
  int b_row = t >> 4, b_col = (t & 15) * 8;
  int a_m = m0 + a_row; if (a_m > M - 1) a_m = M - 1;
  const float* Ap = A + (size_t)a_m * K + a_col;
  const float* Wp = W + (size_t)b_row * N + n0 + b_col;

  for (int k0 = 0; k0 < K; k0 += 16) {
    float4 av0 = *(const float4*)(Ap + k0);
    float4 av1 = *(const float4*)(Ap + k0 + 4);
    float4 bv0 = *(const float4*)(Wp + (size_t)k0 * N);
    float4 bv1 = *(const float4*)(Wp + (size_t)k0 * N + 4);
    __syncthreads();
    As[a_col + 0][a_row] = av0.x;
    As[a_col + 1][a_row] = av0.y;
    As[a_col + 2][a_row] = av0.z;
    As[a_col + 3][a_row] = av0.w;
    As[a_col + 4][a_row] = av1.x;
    As[a_col + 5][a_row] = av1.y;
    As[a_col + 6][a_row] = av1.z;
    As[a_col + 7][a_row] = av1.w;
    *(float4*)&Bs[b_row][b_col]     = bv0;
    *(float4*)&Bs[b_row][b_col + 4] = bv1;
    __syncthreads();
#pragma unroll
    for (int kk = 0; kk < 16; kk++) {
      float a[8], b[8];
      ((float4*)a)[0] = *(const float4*)&As[kk][ty * 8];
      ((float4*)a)[1] = *(const float4*)&As[kk][ty * 8 + 4];
      ((float4*)b)[0] = *(const float4*)&Bs[kk][tx * 8];
      ((float4*)b)[1] = *(const float4*)&Bs[kk][tx * 8 + 4];
#pragma unroll
      for (int i = 0; i < 8; i++)
#pragma unroll
        for (int j = 0; j < 8; j++) acc[i][j] = fmaf(a[i], b[j], acc[i][j]);
    }
  }

#pragma unroll
  for (int i = 0; i < 8; i++) {
    int m = m0 + ty * 8 + i;
    if (m >= M) continue;
    size_t crow = (size_t)m * N;
#pragma unroll
    for (int jj = 0; jj < 2; jj++) {
      int n = n0 + tx * 8 + jj * 4;
      float4 r;
      r.x = acc[i][jj * 4 + 0] + bias[n + 0];
      r.y = acc[i][jj * 4 + 1] + bias[n + 1];
      r.z = acc[i][jj * 4 + 2] + bias[n + 2];
      r.w = acc[i][jj * 4 + 3] + bias[n + 3];
      if (resid) {
        const float4 rv = *(const float4*)&resid[crow + n];
        r.x += rv.x; r.y += rv.y; r.z += rv.z; r.w += rv.w;
      }
      if (relu) {
        r.x = fmaxf(r.x, 0.f); r.y = fmaxf(r.y, 0.f);
        r.z = fmaxf(r.z, 0.f); r.w = fmaxf(r.w, 0.f);
      }
      *(float4*)&C[crow + n] = r;
    }
  }
}

// ---------------- learned-mask projection ----------------
__global__ __launch_bounds__(128)
void lmproj_kernel(const float* __restrict__ src, const float* __restrict__ w,
                   const float* __restrict__ bias, float* __restrict__ dst) {
  int bl = blockIdx.x;
  int t = threadIdx.x;
  int hh = t >> 4, p = t & 15;
  const float* s = src + (size_t)bl * DM_ + hh * DK_;
  float acc = bias[p];
#pragma unroll
  for (int d = 0; d < DK_; d++) acc = fmaf(s[d], w[d * P_ + p], acc);
  dst[((size_t)bl * H_ + hh) * P_ + p] = acc;
}

// ---------------- MFMA flash attention ----------------
// grid = (16 q-tiles, B*H). block = 256 (4 waves; wave w owns q rows l0+w*16..+15).
// MFMA 16x16x32 bf16 layouts (verified, guide §3):
//   A[m=lane&15][k=quad*8+j], B[k=quad*8+j][n=lane&15], C/D col=lane&15 row=quad*4+reg
#define LDK 72   // K / Vt LDS row stride (bf16 elems): 2-way bank aliasing on b128
#define LDQ 40   // kp LDS row stride
__global__ __launch_bounds__(256)
void attn_mfma_kernel(const float* __restrict__ qg, const float* __restrict__ kg,
                      const float* __restrict__ vg, const float* __restrict__ qpg,
                      const float* __restrict__ kpg, float* __restrict__ ctx) {
  __shared__ unsigned short Ks[64 * LDK];   // K[key][dk]      (bf16)
  __shared__ unsigned short Vt[64 * LDK];   // V^T[dk][key]    (bf16)
  __shared__ unsigned short Kp[64 * LDQ];   // kp[key][p], p=16..31 zeroed
  __shared__ unsigned short Ps[4 * 16 * LDK]; // per-wave P[16][64]

  int qt = blockIdx.x, bh = blockIdx.y;
  int b = bh >> 3, hh = bh & 7;
  int l0 = qt * 64;
  int t = threadIdx.x;
  int wv = t >> 6, lane = t & 63;
  int m = lane & 15, quad = lane >> 4;

  // ---- load Q + qp A-fragments (once) ----
  int lq = l0 + wv * 16 + m; if (lq > L_ - 1) lq = L_ - 1;
  const float* qrow = qg + ((size_t)(b * L_ + lq)) * DM_ + hh * DK_;
  bfrag qa[2], qpa;
#pragma unroll
  for (int kc = 0; kc < 2; kc++) {
    float4 a0 = *(const float4*)(qrow + kc * 32 + quad * 8);
    float4 a1 = *(const float4*)(qrow + kc * 32 + quad * 8 + 4);
    qa[kc].q = make_uint4(pack2(a0.x * SCALE_, a0.y * SCALE_),
                          pack2(a0.z * SCALE_, a0.w * SCALE_),
                          pack2(a1.x * SCALE_, a1.y * SCALE_),
                          pack2(a1.z * SCALE_, a1.w * SCALE_));
  }
  if (quad < 2) {
    const float* qprow = qpg + (((size_t)(b * L_ + lq)) * H_ + hh) * P_;
    float4 a0 = *(const float4*)(qprow + quad * 8);
    float4 a1 = *(const float4*)(qprow + quad * 8 + 4);
    qpa.q = make_uint4(pack2(a0.x, a0.y), pack2(a0.z, a0.w),
                       pack2(a1.x, a1.y), pack2(a1.z, a1.w));
  } else {
    qpa.q = make_uint4(0u, 0u, 0u, 0u);
  }

  f32x4 O[4];
#pragma unroll
  for (int nt = 0; nt < 4; nt++) O[nt] = (f32x4){0.f, 0.f, 0.f, 0.f};
  float mrun[4] = {-1e30f, -1e30f, -1e30f, -1e30f};
  float lrun[4] = {0.f, 0.f, 0.f, 0.f};

  int skey = t >> 2, spart = t & 3;

  for (int s0 = 0; s0 < L_; s0 += 64) {
    // ---- stage K / V^T / kp tile (bf16) ----
    int sg = s0 + skey; if (sg > L_ - 1) sg = L_ - 1;
    const float* kr = kg + ((size_t)(b * L_ + sg)) * DM_ + hh * DK_ + spart * 16;
    const float* vr = vg + ((size_t)(b * L_ + sg)) * DM_ + hh * DK_ + spart * 16;
    float4 kf0 = *(const float4*)(kr + 0);
    float4 kf1 = *(const float4*)(kr + 4);
    float4 kf2 = *(const float4*)(kr + 8);
    float4 kf3 = *(const float4*)(kr + 12);
    float4 vf0 = *(const float4*)(vr + 0);
    float4 vf1 = *(const float4*)(vr + 4);
    float4 vf2 = *(const float4*)(vr + 8);
    float4 vf3 = *(const float4*)(vr + 12);
    float4 pf0, pf1, pf2, pf3;
    if (t < 64) {
      int sg2 = s0 + t; if (sg2 > L_ - 1) sg2 = L_ - 1;
      const float* pr = kpg + (((size_t)(b * L_ + sg2)) * H_ + hh) * P_;
      pf0 = *(const float4*)(pr + 0);
      pf1 = *(const float4*)(pr + 4);
      pf2 = *(const float4*)(pr + 8);
      pf3 = *(const float4*)(pr + 12);
    }
    __syncthreads();   // all waves done reading previous tile
    *(uint4*)&Ks[skey * LDK + spart * 16] =
        make_uint4(pack2(kf0.x, kf0.y), pack2(kf0.z, kf0.w),
                   pack2(kf1.x, kf1.y), pack2(kf1.z, kf1.w));
    *(uint4*)&Ks[skey * LDK + spart * 16 + 8] =
        make_uint4(pack2(kf2.x, kf2.y), pack2(kf2.z, kf2.w),
                   pack2(kf3.x, kf3.y), pack2(kf3.z, kf3.w));
    {
      float vv[16] = {vf0.x, vf0.y, vf0.z, vf0.w, vf1.x, vf1.y, vf1.z, vf1.w,
                      vf2.x, vf2.y, vf2.z, vf2.w, vf3.x, vf3.y, vf3.z, vf3.w};
#pragma unroll
      for (int i = 0; i < 16; i++)
        Vt[(spart * 16 + i) * LDK + skey] = f2bf(vv[i]);
    }
    if (t < 64) {
      *(uint4*)&Kp[t * LDQ + 0] = make_uint4(pack2(pf0.x, pf0.y), pack2(pf0.z, pf0.w),
                                             pack2(pf1.x, pf1.y), pack2(pf1.z, pf1.w));
      *(uint4*)&Kp[t * LDQ + 8] = make_uint4(pack2(pf2.x, pf2.y), pack2(pf2.z, pf2.w),
                                             pack2(pf3.x, pf3.y), pack2(pf3.z, pf3.w));
      *(uint4*)&Kp[t * LDQ + 16] = make_uint4(0u, 0u, 0u, 0u);
      *(uint4*)&Kp[t * LDQ + 24] = make_uint4(0u, 0u, 0u, 0u);
    }
    __syncthreads();   // tile staged

    // ---- S = Q K^T (+ tanh(qp kp^T)) via MFMA ----
    f32x4 sacc[4], macc[4];
    const f32x4 zz = (f32x4){0.f, 0.f, 0.f, 0.f};
#pragma unroll
    for (int nt = 0; nt < 4; nt++) {
      const unsigned short* kb = Ks + (nt * 16 + m) * LDK + quad * 8;
      sacc[nt] = __builtin_amdgcn_mfma_f32_16x16x32_bf16(qa[0].b, *(const bf16x8*)kb, zz, 0, 0, 0);
      sacc[nt] = __builtin_amdgcn_mfma_f32_16x16x32_bf16(qa[1].b, *(const bf16x8*)(kb + 32), sacc[nt], 0, 0, 0);
      const unsigned short* kpb = Kp + (nt * 16 + m) * LDQ + quad * 8;
      macc[nt] = __builtin_amdgcn_mfma_f32_16x16x32_bf16(qpa.b, *(const bf16x8*)kpb, zz, 0, 0, 0);
    }

    // ---- online softmax (C-layout: col=m, row=quad*4+r) ----
    float sc[4][4];
#pragma unroll
    for (int nt = 0; nt < 4; nt++) {
      bool oob = (s0 + nt * 16 + m) >= L_;
#pragma unroll
      for (int r = 0; r < 4; r++) {
        float x = macc[nt][r];
        x = fminf(fmaxf(x, -15.f), 15.f);
        float e = __expf(2.f * x);
        float th = (e - 1.f) / (e + 1.f);
        float s = sacc[nt][r] + th;
        sc[nt][r] = oob ? -1e30f : s;
      }
    }
    float mnew[4], alpha[4];
#pragma unroll
    for (int r = 0; r < 4; r++) {
      float rm = fmaxf(fmaxf(sc[0][r], sc[1][r]), fmaxf(sc[2][r], sc[3][r]));
#pragma unroll
      for (int msk = 1; msk < 16; msk <<= 1) rm = fmaxf(rm, __shfl_xor(rm, msk, 64));
      mnew[r] = fmaxf(mrun[r], rm);
      alpha[r] = __expf(mrun[r] - mnew[r]);
      mrun[r] = mnew[r];
    }
    float p[4][4];
    float rs[4] = {0.f, 0.f, 0.f, 0.f};
#pragma unroll
    for (int nt = 0; nt < 4; nt++)
#pragma unroll
      for (int r = 0; r < 4; r++) {
        p[nt][r] = __expf(sc[nt][r] - mnew[r]);
        rs[r] += p[nt][r];
      }
#pragma unroll
    for (int r = 0; r < 4; r++) {
#pragma unroll
      for (int msk = 1; msk < 16; msk <<= 1) rs[r] += __shfl_xor(rs[r], msk, 64);
      lrun[r] = lrun[r] * alpha[r] + rs[r];
    }
    f32x4 av = (f32x4){alpha[0], alpha[1], alpha[2], alpha[3]};
#pragma unroll
    for (int nt = 0; nt < 4; nt++) O[nt] *= av;

    // ---- P: C-layout -> LDS -> A-layout (per-wave region, no barrier) ----
    unsigned short* pw = Ps + wv * (16 * LDK);
#pragma unroll
    for (int nt = 0; nt < 4; nt++)
#pragma unroll
      for (int r = 0; r < 4; r++)
        pw[(quad * 4 + r) * LDK + nt * 16 + m] = f2bf(p[nt][r]);

    bf16x8 pa0 = *(const bf16x8*)(pw + m * LDK + quad * 8);
    bf16x8 pa1 = *(const bf16x8*)(pw + m * LDK + 32 + quad * 8);
#pragma unroll
    for (int nt = 0; nt < 4; nt++) {
      const unsigned short* vb = Vt + (nt * 16 + m) * LDK + quad * 8;
      O[nt] = __builtin_amdgcn_mfma_f32_16x16x32_bf16(pa0, *(const bf16x8*)vb, O[nt], 0, 0, 0);
      O[nt] = __builtin_amdgcn_mfma_f32_16x16x32_bf16(pa1, *(const bf16x8*)(vb + 32), O[nt], 0, 0, 0);
    }
  }

  // ---- store: ctx[l][hh*64 + nt*16 + m], row l = l0 + wv*16 + quad*4 + r ----
  float inv[4];
#pragma unroll
  for (int r = 0; r < 4; r++) inv[r] = 1.f / lrun[r];
#pragma unroll
  for (int r = 0; r < 4; r++) {
    int l = l0 + wv * 16 + quad * 4 + r;
    if (l >= L_) continue;
    float* crow = ctx + ((size_t)(b * L_ + l)) * DM_ + hh * DK_;
#pragma unroll
    for (int nt = 0; nt < 4; nt++) crow[nt * 16 + m] = O[nt][r] * inv[r];
  }
}

// ---------------- layernorm ----------------
__global__ __launch_bounds__(256)
void ln_kernel(const float* __restrict__ a, const float* __restrict__ badd,
               const float* __restrict__ g, const float* __restrict__ be,
               float* __restrict__ o) {
  int row = blockIdx.x;
  int t = threadIdx.x;
  size_t base = (size_t)row * DM_;
  float x0 = a[base + t], x1 = a[base + t + 256];
  if (badd) { x0 += badd[base + t]; x1 += badd[base + t + 256]; }
  float s = x0 + x1;
  float ss = x0 * x0 + x1 * x1;
  s = wave_reduce_sum(s);
  ss = wave_reduce_sum(ss);
  __shared__ float sh_s[4], sh_ss[4];
  int wv = t >> 6, lane = t & 63;
  if (lane == 0) { sh_s[wv] = s; sh_ss[wv] = ss; }
  __syncthreads();
  float S = sh_s[0] + sh_s[1] + sh_s[2] + sh_s[3];
  float SS = sh_ss[0] + sh_ss[1] + sh_ss[2] + sh_ss[3];
  float mean = S * (1.0f / DM_);
  float var = SS * (1.0f / DM_) - mean * mean;
  float rstd = rsqrtf(var + EPS_);
  o[base + t]       = (x0 - mean) * rstd * g[t] + be[t];
  o[base + t + 256] = (x1 - mean) * rstd * g[t + 256] + be[t + 256];
}

// ---------------- final head ----------------
__global__ __launch_bounds__(512)
void final_kernel(const float* __restrict__ h, const float* __restrict__ gn,
                  const float* __restrict__ bn, const float* __restrict__ fcw,
                  const float* __restrict__ fcb, float* __restrict__ out) {
  int b = blockIdx.x;
  int t = threadIdx.x;
  size_t base = ((size_t)b * L_ + (L_ - 1)) * DM_;
  float x = h[base + t];
  float s = wave_reduce_sum(x);
  float ss = wave_reduce_sum(x * x);
  __shared__ float sh_s[8], sh_ss[8];
  int wv = t >> 6, lane = t & 63;
  if (lane == 0) { sh_s[wv] = s; sh_ss[wv] = ss; }
  __syncthreads();
  float S = 0.f, SS = 0.f;
#pragma unroll
  for (int i = 0; i < 8; i++) { S += sh_s[i]; SS += sh_ss[i]; }
  float mean = S * (1.0f / DM_);
  float var = SS * (1.0f / DM_) - mean * mean;
  float rstd = rsqrtf(var + EPS_);
  __shared__ float hn[DM_];
  hn[t] = (x - mean) * rstd * gn[t] + bn[t];
  __syncthreads();
  if (t < PRED_) {
    float acc = fcb[t];
#pragma unroll 8
    for (int d = 0; d < DM_; d++) acc = fmaf(hn[d], fcw[d * PRED_ + t], acc);
    out[b * PRED_ + t] = acc;
  }
}

// ---------------- driver ----------------
extern "C" void kernel_launch(void* const* d_in, const int* in_sizes, int n_in,
                              void* d_out, int out_size, void* d_ws, size_t ws_size,
                              hipStream_t stream) {
  const float* x     = (const float*)d_in[0];
  const float* emb_w = (const float*)d_in[1];
  const float* emb_b = (const float*)d_in[2];
  const float* pe    = (const float*)d_in[3];
  const float* Wq = (const float*)d_in[4];  const float* bq = (const float*)d_in[5];
  const float* Wk = (const float*)d_in[6];  const float* bk = (const float*)d_in[7];
  const float* Wv = (const float*)d_in[8];  const float* bv = (const float*)d_in[9];
  const float* Wo = (const float*)d_in[10]; const float* bo = (const float*)d_in[11];
  const float* W1 = (const float*)d_in[12]; const float* b1 = (const float*)d_in[13];
  const float* W2 = (const float*)d_in[14]; const float* b2 = (const float*)d_in[15];
  const float* g1 = (const float*)d_in[16]; const float* be1 = (const float*)d_in[17];
  const float* g2 = (const float*)d_in[18]; const float* be2 = (const float*)d_in[19];
  const float* lm_qw = (const float*)d_in[20]; const float* lm_qb = (const float*)d_in[21];
  const float* lm_kw = (const float*)d_in[22]; const float* lm_kb = (const float*)d_in[23];
  const float* gn = (const float*)d_in[24]; const float* bn = (const float*)d_in[25];
  const float* fc_w = (const float*)d_in[26]; const float* fc_b = (const float*)d_in[27];
  float* out = (float*)d_out;

  float* ws = (float*)d_ws;
  const size_t ROWS = (size_t)B_ * L_;          // 8000
  float* h    = ws;
  float* q    = h   + ROWS * DM_;
  float* k    = q   + ROWS * DM_;
  float* v    = k   + ROWS * DM_;
  float* ctx  = v   + ROWS * DM_;
  float* t0   = ctx + ROWS * DM_;
  float* qp   = t0  + ROWS * DM_;
  float* kp   = qp  + ROWS * H_ * P_;
  float* ffn1 = q;   // aliases q..ctx during FFN

  embed_kernel<<<dim3((unsigned)ROWS), 512, 0, stream>>>(x, emb_w, emb_b, pe, h);

  dim3 gqkv(DM_ / 128, (8000 + 127) / 128);
  dim3 gffn1(DFF_ / 128, (8000 + 127) / 128);
  dim3 gattn((L_ + 63) / 64, B_ * H_);           // (16, 64)

  for (int i = 0; i < NL_; i++) {
    const float* Wq_i = Wq + (size_t)i * DM_ * DM_;
    const float* Wk_i = Wk + (size_t)i * DM_ * DM_;
    const float* Wv_i = Wv + (size_t)i * DM_ * DM_;
    const float* Wo_i = Wo + (size_t)i * DM_ * DM_;
    const float* W1_i = W1 + (size_t)i * DM_ * DFF_;
    const float* W2_i = W2 + (size_t)i * DFF_ * DM_;

    gemm_kernel<<<gqkv, 256, 0, stream>>>(h, Wq_i, bq + i * DM_, nullptr, q, 8000, DM_, DM_, 0);
    gemm_kernel<<<gqkv, 256, 0, stream>>>(h, Wk_i, bk + i * DM_, nullptr, k, 8000, DM_, DM_, 0);
    gemm_kernel<<<gqkv, 256, 0, stream>>>(h, Wv_i, bv + i * DM_, nullptr, v, 8000, DM_, DM_, 0);

    lmproj_kernel<<<dim3((unsigned)ROWS), 128, 0, stream>>>(q, lm_qw, lm_qb, qp);
    lmproj_kernel<<<dim3((unsigned)ROWS), 128, 0, stream>>>(k, lm_kw, lm_kb, kp);

    attn_mfma_kernel<<<gattn, 256, 0, stream>>>(q, k, v, qp, kp, ctx);

    gemm_kernel<<<gqkv, 256, 0, stream>>>(ctx, Wo_i, bo + i * DM_, h, t0, 8000, DM_, DM_, 0);
    ln_kernel<<<dim3((unsigned)ROWS), 256, 0, stream>>>(t0, nullptr, g1 + i * DM_, be1 + i * DM_, h);

    gemm_kernel<<<gffn1, 256, 0, stream>>>(h, W1_i, b1 + i * DFF_, nullptr, ffn1, 8000, DM_, DFF_, 1);
    gemm_kernel<<<gqkv, 256, 0, stream>>>(ffn1, W2_i, b2 + i * DM_, nullptr, t0, 8000, DFF_, DM_, 0);

    ln_kernel<<<dim3((unsigned)ROWS), 256, 0, stream>>>(h, t0, g2 + i * DM_, be2 + i * DM_, h);
    ln_kernel<<<dim3((unsigned)ROWS), 256, 0, stream>>>(h, t0, g2 + i * DM_, be2 + i * DM_, h);
  }

  final_kernel<<<B_, 512, 0, stream>>>(h, gn, bn, fc_w, fc_b, out);
}

// Round 3
// 1418.362 us; speedup vs baseline: 5.9490x; 2.7742x over previous
//
#include <hip/hip_runtime.h>
#include <math.h>

// Problem constants (PCUTransformer)
#define B_    8
#define L_    1000
#define F_    7
#define DM_   512
#define H_    8
#define DFF_  2048
#define NL_   4
#define PRED_ 50
#define DK_   64
#define P_    16
#define EPS_  1e-5f
#define SCALE_ 0.125f   // 1/sqrt(64)
#define QKVS  1536      // fused qkv row stride

typedef unsigned short u16;
typedef __bf16 bf16x8 __attribute__((ext_vector_type(8)));
typedef float  f32x4  __attribute__((ext_vector_type(4)));

// ---------------- helpers ----------------
__device__ inline float wave_reduce_sum(float x) {
#pragma unroll
  for (int off = 32; off >= 1; off >>= 1) x += __shfl_xor(x, off, 64);
  return x;
}
__device__ inline u16 f2bf(float f) {   // RNE float->bf16 bits
  unsigned int u = __float_as_uint(f);
  unsigned int r = u + 0x7FFFu + ((u >> 16) & 1u);
  return (u16)(r >> 16);
}
__device__ inline float bf2f(u16 u) { return __uint_as_float(((unsigned int)u) << 16); }

union bfrag { bf16x8 b; uint4 q; u16 u[8]; };

// async global->LDS, 16B per lane; lds dest = wave-uniform base + lane*16
__device__ inline void gload16(const u16* g, u16* l) {
  __builtin_amdgcn_global_load_lds(
      (const __attribute__((address_space(1))) void*)g,
      (__attribute__((address_space(3))) void*)l, 16, 0, 0);
}

// ---------------- weight transpose-convert: out[n][k] = bf16(in[k][n]) ------
// grid (N/32, K/32, NL), block 256 (32x8)
__global__ __launch_bounds__(256)
void transpose_w(const float* __restrict__ in, u16* __restrict__ out,
                 int K, int N, size_t in_lstride, size_t out_lstride,
                 int row_off, int out_ld) {
  __shared__ float tile[32][33];
  int z = blockIdx.z;
  int kk0 = blockIdx.y * 32, nn0 = blockIdx.x * 32;
  int tx = threadIdx.x & 31, ty = threadIdx.x >> 5;
  const float* ip = in + z * in_lstride;
  u16* op = out + z * out_lstride;
#pragma unroll
  for (int i = 0; i < 4; i++)
    tile[ty + i * 8][tx] = ip[(size_t)(kk0 + ty + i * 8) * N + nn0 + tx];
  __syncthreads();
#pragma unroll
  for (int i = 0; i < 4; i++)
    op[(size_t)(row_off + nn0 + ty + i * 8) * out_ld + kk0 + tx] = f2bf(tile[tx][ty + i * 8]);
}

// ---------------- qkv bias concat: bqkv[l][0:512|512:1024|1024:1536] --------
__global__ __launch_bounds__(256)
void concat_bias(const float* __restrict__ bq, const float* __restrict__ bk,
                 const float* __restrict__ bv, float* __restrict__ bqkv) {
  int i = blockIdx.x * 256 + threadIdx.x;     // NL*1536
  int l = i / QKVS, j = i % QKVS;
  float v = (j < 512) ? bq[l * 512 + j] : (j < 1024) ? bk[l * 512 + j - 512]
                                                     : bv[l * 512 + j - 1024];
  bqkv[i] = v;
}

// ---------------- embedding: h = x @ emb_w + emb_b + pe (fp32 + bf16) -------
__global__ __launch_bounds__(512)
void embed_kernel(const float* __restrict__ x, const float* __restrict__ emb_w,
                  const float* __restrict__ emb_b, const float* __restrict__ pe,
                  float* __restrict__ h, u16* __restrict__ h16) {
  int bl = blockIdx.x;
  int l = bl % L_;
  int d = threadIdx.x;
  const float* xr = x + (size_t)bl * F_;
  float acc = emb_b[d] + pe[(size_t)l * DM_ + d];
#pragma unroll
  for (int f = 0; f < F_; f++) acc = fmaf(xr[f], emb_w[f * DM_ + d], acc);
  h[(size_t)bl * DM_ + d] = acc;
  h16[(size_t)bl * DM_ + d] = f2bf(acc);
}

// ---------------- bf16 MFMA GEMM: C = A[M,K] @ Bt[N,K]^T + bias -------------
// m97 structure: 128xBN tile, BK=32, global_load_lds(16B), XOR chunk swizzle.
// 256 threads = 4 waves in 2x2 of 64 x BN/2.
template<int BN>
__global__ __launch_bounds__(256)
void gemm16(const u16* __restrict__ A, const u16* __restrict__ Bt,
            const float* __restrict__ bias, const float* __restrict__ resid,
            float* __restrict__ C32, u16* __restrict__ C16,
            int M, int K, int N, int relu) {
  constexpr int NTW = BN / 32;   // 16-col MFMA tiles per wave
  constexpr int BJ  = BN / 64;   // B staging insts per wave
  __shared__ u16 As[128 * 32];
  __shared__ u16 Bs[BN * 32];
  int t = threadIdx.x;
  int w = t >> 6, lane = t & 63;
  int wr = w >> 1, wc = w & 1;
  int mloc = lane & 15, quad = lane >> 4;
  int m0 = blockIdx.y * 128, n0 = blockIdx.x * BN;

  // staging pointers (lane's LDS slot = row(lane>>2), chunk(lane&3); it holds
  // global chunk (lane&3)^((row>>1)&3) -> read side un-permutes; 2-way banks)
  const u16* agp[2]; u16* alds[2];
#pragma unroll
  for (int j = 0; j < 2; j++) {
    int r = w * 32 + j * 16 + (lane >> 2);
    int gm = m0 + r; if (gm > M - 1) gm = M - 1;
    int ch = (lane & 3) ^ ((r >> 1) & 3);
    agp[j] = A + (size_t)gm * K + ch * 8;
    alds[j] = As + (w * 32 + j * 16) * 32;
  }
  const u16* bgp[BJ]; u16* blds[BJ];
#pragma unroll
  for (int j = 0; j < BJ; j++) {
    int r = w * (16 * BJ) + j * 16 + (lane >> 2);
    int ch = (lane & 3) ^ ((r >> 1) & 3);
    bgp[j] = Bt + (size_t)(n0 + r) * K + ch * 8;
    blds[j] = Bs + (w * (16 * BJ) + j * 16) * 32;
  }
  // fragment read pointers (constant across K-iters)
  const u16* apt[4];
#pragma unroll
  for (int mi = 0; mi < 4; mi++) {
    int tr = wr * 64 + mi * 16 + mloc;
    apt[mi] = As + tr * 32 + (quad ^ ((tr >> 1) & 3)) * 8;
  }
  const u16* bpt[NTW];
#pragma unroll
  for (int nt = 0; nt < NTW; nt++) {
    int tr = wc * (BN / 2) + nt * 16 + mloc;
    bpt[nt] = Bs + tr * 32 + (quad ^ ((tr >> 1) & 3)) * 8;
  }

  f32x4 acc[4][NTW];
#pragma unroll
  for (int mi = 0; mi < 4; mi++)
#pragma unroll
    for (int nt = 0; nt < NTW; nt++) acc[mi][nt] = (f32x4){0.f, 0.f, 0.f, 0.f};

  for (int k0 = 0; k0 < K; k0 += 32) {
    __syncthreads();                  // prev tile's ds_reads retired
    gload16(agp[0] + k0, alds[0]);
    gload16(agp[1] + k0, alds[1]);
#pragma unroll
    for (int j = 0; j < BJ; j++) gload16(bgp[j] + k0, blds[j]);
    __syncthreads();                  // vmcnt(0) drain: tile staged
    bf16x8 af[4], bv[NTW];
#pragma unroll
    for (int mi = 0; mi < 4; mi++) af[mi] = *(const bf16x8*)apt[mi];
#pragma unroll
    for (int nt = 0; nt < NTW; nt++) bv[nt] = *(const bf16x8*)bpt[nt];
#pragma unroll
    for (int mi = 0; mi < 4; mi++)
#pragma unroll
      for (int nt = 0; nt < NTW; nt++)
        acc[mi][nt] = __builtin_amdgcn_mfma_f32_16x16x32_bf16(af[mi], bv[nt], acc[mi][nt], 0, 0, 0);
  }

  // epilogue: C row m = quad*4+r, col n = mloc (verified C/D layout)
#pragma unroll
  for (int mi = 0; mi < 4; mi++) {
#pragma unroll
    for (int r = 0; r < 4; r++) {
      int m = m0 + wr * 64 + mi * 16 + quad * 4 + r;
      if (m >= M) continue;
      size_t crow = (size_t)m * N;
#pragma unroll
      for (int nt = 0; nt < NTW; nt++) {
        int n = n0 + wc * (BN / 2) + nt * 16 + mloc;
        float vsum = acc[mi][nt][r] + bias[n];
        if (resid) vsum += resid[crow + n];
        if (relu) vsum = fmaxf(vsum, 0.f);
        if (C32) C32[crow + n] = vsum;
        if (C16) C16[crow + n] = f2bf(vsum);
      }
    }
  }
}

// ---------------- learned-mask projection (bf16 in/out) ---------------------
__global__ __launch_bounds__(128)
void lmproj_kernel(const u16* __restrict__ src, int col0, const float* __restrict__ w,
                   const float* __restrict__ bias, u16* __restrict__ dst) {
  int bl = blockIdx.x;
  int t = threadIdx.x;
  int hh = t >> 4, p = t & 15;
  const u16* s = src + (size_t)bl * QKVS + col0 + hh * DK_;
  float acc = bias[p];
#pragma unroll
  for (int d = 0; d < DK_; d++) acc = fmaf(bf2f(s[d]), w[d * P_ + p], acc);
  dst[((size_t)bl * H_ + hh) * P_ + p] = f2bf(acc);
}

// ---------------- MFMA flash attention (bf16 I/O) ---------------------------
#define LDK 72
#define LDQ 40
__global__ __launch_bounds__(256)
void attn_mfma_kernel(const u16* __restrict__ qkv, const u16* __restrict__ qpg,
                      const u16* __restrict__ kpg, u16* __restrict__ ctx) {
  __shared__ u16 Ks[64 * LDK];   // K[key][dk]
  __shared__ u16 Vt[64 * LDK];   // V^T[dk][key]
  __shared__ u16 Kp[64 * LDQ];   // kp[key][p], p=16..31 zeroed
  __shared__ u16 Ps[4 * 16 * LDK];

  int qt = blockIdx.x, bh = blockIdx.y;
  int b = bh >> 3, hh = bh & 7;
  int l0 = qt * 64;
  int t = threadIdx.x;
  int wv = t >> 6, lane = t & 63;
  int m = lane & 15, quad = lane >> 4;

  int lq = l0 + wv * 16 + m; if (lq > L_ - 1) lq = L_ - 1;
  const u16* qrow = qkv + (size_t)(b * L_ + lq) * QKVS + hh * DK_;
  bf16x8 qa0 = *(const bf16x8*)(qrow + quad * 8);
  bf16x8 qa1 = *(const bf16x8*)(qrow + 32 + quad * 8);
  bfrag qpa;
  if (quad < 2) {
    const u16* qprow = qpg + ((size_t)(b * L_ + lq) * H_ + hh) * P_;
    qpa.q = *(const uint4*)(qprow + quad * 8);
  } else {
    qpa.q = make_uint4(0u, 0u, 0u, 0u);
  }

  f32x4 O[4];
#pragma unroll
  for (int nt = 0; nt < 4; nt++) O[nt] = (f32x4){0.f, 0.f, 0.f, 0.f};
  float mrun[4] = {-1e30f, -1e30f, -1e30f, -1e30f};
  float lrun[4] = {0.f, 0.f, 0.f, 0.f};

  int skey = t >> 2, spart = t & 3;

  for (int s0 = 0; s0 < L_; s0 += 64) {
    int sg = s0 + skey; if (sg > L_ - 1) sg = L_ - 1;
    const u16* kr = qkv + (size_t)(b * L_ + sg) * QKVS + 512 + hh * DK_ + spart * 16;
    const u16* vr = qkv + (size_t)(b * L_ + sg) * QKVS + 1024 + hh * DK_ + spart * 16;
    uint4 kq0 = *(const uint4*)(kr);
    uint4 kq1 = *(const uint4*)(kr + 8);
    union { uint4 q[2]; u16 u[16]; } vu;
    vu.q[0] = *(const uint4*)(vr);
    vu.q[1] = *(const uint4*)(vr + 8);
    uint4 p0, p1;
    if (t < 64) {
      int sg2 = s0 + t; if (sg2 > L_ - 1) sg2 = L_ - 1;
      const u16* pr = kpg + ((size_t)(b * L_ + sg2) * H_ + hh) * P_;
      p0 = *(const uint4*)(pr);
      p1 = *(const uint4*)(pr + 8);
    }
    __syncthreads();
    *(uint4*)&Ks[skey * LDK + spart * 16]     = kq0;
    *(uint4*)&Ks[skey * LDK + spart * 16 + 8] = kq1;
#pragma unroll
    for (int i = 0; i < 16; i++) Vt[(spart * 16 + i) * LDK + skey] = vu.u[i];
    if (t < 64) {
      *(uint4*)&Kp[t * LDQ]      = p0;
      *(uint4*)&Kp[t * LDQ + 8]  = p1;
      *(uint4*)&Kp[t * LDQ + 16] = make_uint4(0u, 0u, 0u, 0u);
      *(uint4*)&Kp[t * LDQ + 24] = make_uint4(0u, 0u, 0u, 0u);
    }
    __syncthreads();

    f32x4 sacc[4], macc[4];
    const f32x4 zz = (f32x4){0.f, 0.f, 0.f, 0.f};
#pragma unroll
    for (int nt = 0; nt < 4; nt++) {
      const u16* kb = Ks + (nt * 16 + m) * LDK + quad * 8;
      sacc[nt] = __builtin_amdgcn_mfma_f32_16x16x32_bf16(qa0, *(const bf16x8*)kb, zz, 0, 0, 0);
      sacc[nt] = __builtin_amdgcn_mfma_f32_16x16x32_bf16(qa1, *(const bf16x8*)(kb + 32), sacc[nt], 0, 0, 0);
      const u16* kpb = Kp + (nt * 16 + m) * LDQ + quad * 8;
      macc[nt] = __builtin_amdgcn_mfma_f32_16x16x32_bf16(qpa.b, *(const bf16x8*)kpb, zz, 0, 0, 0);
    }

    float sc[4][4];
#pragma unroll
    for (int nt = 0; nt < 4; nt++) {
      bool oob = (s0 + nt * 16 + m) >= L_;
#pragma unroll
      for (int r = 0; r < 4; r++) {
        float x = macc[nt][r];
        x = fminf(fmaxf(x, -15.f), 15.f);
        float e = __expf(2.f * x);
        float th = (e - 1.f) / (e + 1.f);
        float s = sacc[nt][r] * SCALE_ + th;
        sc[nt][r] = oob ? -1e30f : s;
      }
    }
    float mnew[4], alpha[4];
#pragma unroll
    for (int r = 0; r < 4; r++) {
      float rm = fmaxf(fmaxf(sc[0][r], sc[1][r]), fmaxf(sc[2][r], sc[3][r]));
#pragma unroll
      for (int msk = 1; msk < 16; msk <<= 1) rm = fmaxf(rm, __shfl_xor(rm, msk, 64));
      mnew[r] = fmaxf(mrun[r], rm);
      alpha[r] = __expf(mrun[r] - mnew[r]);
      mrun[r] = mnew[r];
    }
    float p[4][4];
    float rs[4] = {0.f, 0.f, 0.f, 0.f};
#pragma unroll
    for (int nt = 0; nt < 4; nt++)
#pragma unroll
      for (int r = 0; r < 4; r++) {
        p[nt][r] = __expf(sc[nt][r] - mnew[r]);
        rs[r] += p[nt][r];
      }
#pragma unroll
    for (int r = 0; r < 4; r++) {
#pragma unroll
      for (int msk = 1; msk < 16; msk <<= 1) rs[r] += __shfl_xor(rs[r], msk, 64);
      lrun[r] = lrun[r] * alpha[r] + rs[r];
    }
    f32x4 av = (f32x4){alpha[0], alpha[1], alpha[2], alpha[3]};
#pragma unroll
    for (int nt = 0; nt < 4; nt++) O[nt] *= av;

    u16* pw = Ps + wv * (16 * LDK);
#pragma unroll
    for (int nt = 0; nt < 4; nt++)
#pragma unroll
      for (int r = 0; r < 4; r++)
        pw[(quad * 4 + r) * LDK + nt * 16 + m] = f2bf(p[nt][r]);

    bf16x8 pa0 = *(const bf16x8*)(pw + m * LDK + quad * 8);
    bf16x8 pa1 = *(const bf16x8*)(pw + m * LDK + 32 + quad * 8);
#pragma unroll
    for (int nt = 0; nt < 4; nt++) {
      const u16* vb = Vt + (nt * 16 + m) * LDK + quad * 8;
      O[nt] = __builtin_amdgcn_mfma_f32_16x16x32_bf16(pa0, *(const bf16x8*)vb, O[nt], 0, 0, 0);
      O[nt] = __builtin_amdgcn_mfma_f32_16x16x32_bf16(pa1, *(const bf16x8*)(vb + 32), O[nt], 0, 0, 0);
    }
  }

  float inv[4];
#pragma unroll
  for (int r = 0; r < 4; r++) inv[r] = 1.f / lrun[r];
#pragma unroll
  for (int r = 0; r < 4; r++) {
    int l = l0 + wv * 16 + quad * 4 + r;
    if (l >= L_) continue;
    u16* crow = ctx + ((size_t)(b * L_ + l)) * DM_ + hh * DK_;
#pragma unroll
    for (int nt = 0; nt < 4; nt++) crow[nt * 16 + m] = f2bf(O[nt][r] * inv[r]);
  }
}

// ---------------- layernorm: out = LN(a (+badd)) * g + be -------------------
__global__ __launch_bounds__(256)
void ln_kernel(const float* __restrict__ a, const float* __restrict__ badd,
               const float* __restrict__ g, const float* __restrict__ be,
               float* __restrict__ o, u16* __restrict__ o16) {
  int row = blockIdx.x;
  int t = threadIdx.x;
  size_t base = (size_t)row * DM_;
  float x0 = a[base + t], x1 = a[base + t + 256];
  if (badd) { x0 += badd[base + t]; x1 += badd[base + t + 256]; }
  float s = wave_reduce_sum(x0 + x1);
  float ss = wave_reduce_sum(x0 * x0 + x1 * x1);
  __shared__ float sh_s[4], sh_ss[4];
  int wv = t >> 6, lane = t & 63;
  if (lane == 0) { sh_s[wv] = s; sh_ss[wv] = ss; }
  __syncthreads();
  float S = sh_s[0] + sh_s[1] + sh_s[2] + sh_s[3];
  float SS = sh_ss[0] + sh_ss[1] + sh_ss[2] + sh_ss[3];
  float mean = S * (1.0f / DM_);
  float var = SS * (1.0f / DM_) - mean * mean;
  float rstd = rsqrtf(var + EPS_);
  float r0 = (x0 - mean) * rstd * g[t] + be[t];
  float r1 = (x1 - mean) * rstd * g[t + 256] + be[t + 256];
  o[base + t] = r0; o[base + t + 256] = r1;
  if (o16) { o16[base + t] = f2bf(r0); o16[base + t + 256] = f2bf(r1); }
}

// ---------------- fused double layernorm: h = LN(LN(h+y)+y) -----------------
__global__ __launch_bounds__(256)
void ln2x_kernel(const float* __restrict__ hin, const float* __restrict__ y,
                 const float* __restrict__ g, const float* __restrict__ be,
                 float* __restrict__ o32, u16* __restrict__ o16) {
  int row = blockIdx.x;
  int t = threadIdx.x;
  size_t base = (size_t)row * DM_;
  float y0 = y[base + t], y1 = y[base + t + 256];
  float x0 = hin[base + t] + y0, x1 = hin[base + t + 256] + y1;
  __shared__ float sh_s[4], sh_ss[4];
  int wv = t >> 6, lane = t & 63;
  float g0 = g[t], g1v = g[t + 256], b0 = be[t], b1v = be[t + 256];

  float s = wave_reduce_sum(x0 + x1);
  float ss = wave_reduce_sum(x0 * x0 + x1 * x1);
  if (lane == 0) { sh_s[wv] = s; sh_ss[wv] = ss; }
  __syncthreads();
  float S = sh_s[0] + sh_s[1] + sh_s[2] + sh_s[3];
  float SS = sh_ss[0] + sh_ss[1] + sh_ss[2] + sh_ss[3];
  float mean = S * (1.0f / DM_);
  float var = SS * (1.0f / DM_) - mean * mean;
  float rstd = rsqrtf(var + EPS_);
  float h20 = (x0 - mean) * rstd * g0 + b0 + y0;   // h2 + y for pass 2
  float h21 = (x1 - mean) * rstd * g1v + b1v + y1;
  __syncthreads();

  s = wave_reduce_sum(h20 + h21);
  ss = wave_reduce_sum(h20 * h20 + h21 * h21);
  if (lane == 0) { sh_s[wv] = s; sh_ss[wv] = ss; }
  __syncthreads();
  S = sh_s[0] + sh_s[1] + sh_s[2] + sh_s[3];
  SS = sh_ss[0] + sh_ss[1] + sh_ss[2] + sh_ss[3];
  mean = S * (1.0f / DM_);
  var = SS * (1.0f / DM_) - mean * mean;
  rstd = rsqrtf(var + EPS_);
  float r0 = (h20 - mean) * rstd * g0 + b0;
  float r1 = (h21 - mean) * rstd * g1v + b1v;
  o32[base + t] = r0; o32[base + t + 256] = r1;
  if (o16) { o16[base + t] = f2bf(r0); o16[base + t + 256] = f2bf(r1); }
}

// ---------------- final head ----------------
__global__ __launch_bounds__(512)
void final_kernel(const float* __restrict__ h, const float* __restrict__ gn,
                  const float* __restrict__ bn, const float* __restrict__ fcw,
                  const float* __restrict__ fcb, float* __restrict__ out) {
  int b = blockIdx.x;
  int t = threadIdx.x;
  size_t base = ((size_t)b * L_ + (L_ - 1)) * DM_;
  float x = h[base + t];
  float s = wave_reduce_sum(x);
  float ss = wave_reduce_sum(x * x);
  __shared__ float sh_s[8], sh_ss[8];
  int wv = t >> 6, lane = t & 63;
  if (lane == 0) { sh_s[wv] = s; sh_ss[wv] = ss; }
  __syncthreads();
  float S = 0.f, SS = 0.f;
#pragma unroll
  for (int i = 0; i < 8; i++) { S += sh_s[i]; SS += sh_ss[i]; }
  float mean = S * (1.0f / DM_);
  float var = SS * (1.0f / DM_) - mean * mean;
  float rstd = rsqrtf(var + EPS_);
  __shared__ float hn[DM_];
  hn[t] = (x - mean) * rstd * gn[t] + bn[t];
  __syncthreads();
  if (t < PRED_) {
    float acc = fcb[t];
#pragma unroll 8
    for (int d = 0; d < DM_; d++) acc = fmaf(hn[d], fcw[d * PRED_ + t], acc);
    out[b * PRED_ + t] = acc;
  }
}

// ---------------- driver ----------------
extern "C" void kernel_launch(void* const* d_in, const int* in_sizes, int n_in,
                              void* d_out, int out_size, void* d_ws, size_t ws_size,
                              hipStream_t stream) {
  const float* x     = (const float*)d_in[0];
  const float* emb_w = (const float*)d_in[1];
  const float* emb_b = (const float*)d_in[2];
  const float* pe    = (const float*)d_in[3];
  const float* Wq = (const float*)d_in[4];  const float* bq = (const float*)d_in[5];
  const float* Wk = (const float*)d_in[6];  const float* bk = (const float*)d_in[7];
  const float* Wv = (const float*)d_in[8];  const float* bv = (const float*)d_in[9];
  const float* Wo = (const float*)d_in[10]; const float* bo = (const float*)d_in[11];
  const float* W1 = (const float*)d_in[12]; const float* b1 = (const float*)d_in[13];
  const float* W2 = (const float*)d_in[14]; const float* b2 = (const float*)d_in[15];
  const float* g1 = (const float*)d_in[16]; const float* be1 = (const float*)d_in[17];
  const float* g2 = (const float*)d_in[18]; const float* be2 = (const float*)d_in[19];
  const float* lm_qw = (const float*)d_in[20]; const float* lm_qb = (const float*)d_in[21];
  const float* lm_kw = (const float*)d_in[22]; const float* lm_kb = (const float*)d_in[23];
  const float* gn = (const float*)d_in[24]; const float* bn = (const float*)d_in[25];
  const float* fc_w = (const float*)d_in[26]; const float* fc_b = (const float*)d_in[27];
  float* out = (float*)d_out;

  const size_t ROWS = (size_t)B_ * L_;     // 8000
  // workspace layout (103.0 MB total; qkv16+ctx16 contiguous => ffn1 alias)
  u16* qkv16 = (u16*)d_ws;                               // [8000][1536]
  u16* ctx16 = qkv16 + ROWS * QKVS;                      // [8000][512]
  u16* ffn1  = qkv16;                                    // [8000][2048] alias
  u16* h16   = ctx16 + ROWS * DM_;                       // [8000][512]
  u16* qp16  = h16 + ROWS * DM_;                         // [8000][128]
  u16* kp16  = qp16 + ROWS * H_ * P_;
  u16* Wqkv_t = kp16 + ROWS * H_ * P_;                   // [NL][1536][512]
  u16* Wo_t   = Wqkv_t + (size_t)NL_ * QKVS * DM_;       // [NL][512][512]
  u16* W1_t   = Wo_t + (size_t)NL_ * DM_ * DM_;          // [NL][2048][512]
  u16* W2_t   = W1_t + (size_t)NL_ * DFF_ * DM_;         // [NL][512][2048]
  float* h32  = (float*)(W2_t + (size_t)NL_ * DM_ * DFF_);
  float* t0   = h32 + ROWS * DM_;
  float* bqkv = t0 + ROWS * DM_;                         // [NL][1536]

  // weight conversions (every launch; ~30 us total)
  transpose_w<<<dim3(16, 16, NL_), 256, 0, stream>>>(Wq, Wqkv_t, DM_, DM_, (size_t)DM_ * DM_, (size_t)QKVS * DM_, 0, DM_);
  transpose_w<<<dim3(16, 16, NL_), 256, 0, stream>>>(Wk, Wqkv_t, DM_, DM_, (size_t)DM_ * DM_, (size_t)QKVS * DM_, 512, DM_);
  transpose_w<<<dim3(16, 16, NL_), 256, 0, stream>>>(Wv, Wqkv_t, DM_, DM_, (size_t)DM_ * DM_, (size_t)QKVS * DM_, 1024, DM_);
  transpose_w<<<dim3(16, 16, NL_), 256, 0, stream>>>(Wo, Wo_t, DM_, DM_, (size_t)DM_ * DM_, (size_t)DM_ * DM_, 0, DM_);
  transpose_w<<<dim3(64, 16, NL_), 256, 0, stream>>>(W1, W1_t, DM_, DFF_, (size_t)DM_ * DFF_, (size_t)DFF_ * DM_, 0, DM_);
  transpose_w<<<dim3(16, 64, NL_), 256, 0, stream>>>(W2, W2_t, DFF_, DM_, (size_t)DFF_ * DM_, (size_t)DM_ * DFF_, 0, DFF_);
  concat_bias<<<NL_ * QKVS / 256, 256, 0, stream>>>(bq, bk, bv, bqkv);

  embed_kernel<<<dim3((unsigned)ROWS), 512, 0, stream>>>(x, emb_w, emb_b, pe, h32, h16);

  dim3 g_qkv(QKVS / 128, 63);    // (12, 63)
  dim3 g_ffn1(DFF_ / 128, 63);   // (16, 63)
  dim3 g_n512(DM_ / 64, 63);     // (8, 63)  BN=64
  dim3 g_attn(16, B_ * H_);

  for (int i = 0; i < NL_; i++) {
    gemm16<128><<<g_qkv, 256, 0, stream>>>(h16, Wqkv_t + (size_t)i * QKVS * DM_,
        bqkv + i * QKVS, nullptr, nullptr, qkv16, 8000, DM_, QKVS, 0);

    lmproj_kernel<<<dim3((unsigned)ROWS), 128, 0, stream>>>(qkv16, 0, lm_qw, lm_qb, qp16);
    lmproj_kernel<<<dim3((unsigned)ROWS), 128, 0, stream>>>(qkv16, 512, lm_kw, lm_kb, kp16);

    attn_mfma_kernel<<<g_attn, 256, 0, stream>>>(qkv16, qp16, kp16, ctx16);

    gemm16<64><<<g_n512, 256, 0, stream>>>(ctx16, Wo_t + (size_t)i * DM_ * DM_,
        bo + i * DM_, h32, t0, nullptr, 8000, DM_, DM_, 0);
    ln_kernel<<<dim3((unsigned)ROWS), 256, 0, stream>>>(t0, nullptr, g1 + i * DM_, be1 + i * DM_, h32, h16);

    gemm16<128><<<g_ffn1, 256, 0, stream>>>(h16, W1_t + (size_t)i * DFF_ * DM_,
        b1 + i * DFF_, nullptr, nullptr, ffn1, 8000, DM_, DFF_, 1);
    gemm16<64><<<g_n512, 256, 0, stream>>>(ffn1, W2_t + (size_t)i * DM_ * DFF_,
        b2 + i * DM_, nullptr, t0, nullptr, 8000, DFF_, DM_, 0);

    ln2x_kernel<<<dim3((unsigned)ROWS), 256, 0, stream>>>(h32, t0, g2 + i * DM_, be2 + i * DM_, h32, h16);
  }

  final_kernel<<<B_, 512, 0, stream>>>(h32, gn, bn, fc_w, fc_b, out);
}

// Round 4
// 1345.622 us; speedup vs baseline: 6.2706x; 1.0541x over previous
//
#include <hip/hip_runtime.h>
#include <math.h>

// Problem constants (PCUTransformer)
#define B_    8
#define L_    1000
#define F_    7
#define DM_   512
#define H_    8
#define DFF_  2048
#define NL_   4
#define PRED_ 50
#define DK_   64
#define P_    16
#define EPS_  1e-5f
#define QKVS  1536      // fused qkv row stride

#define L2E_   1.4426950408889634f
#define C_QS   0.18033688011112042f   // 0.125 * log2(e) folded into q
#define WS_QP  16.0f                  // lmproj-q weight compensation: 16*C_QS = 2*log2e
#define BS_QP  2.8853900817779268f    // 2*log2(e) bias scale

typedef unsigned short u16;
typedef __bf16 bf16x8 __attribute__((ext_vector_type(8)));
typedef float  f32x4  __attribute__((ext_vector_type(4)));

// ---------------- helpers ----------------
__device__ inline float wave_reduce_sum(float x) {
#pragma unroll
  for (int off = 32; off >= 1; off >>= 1) x += __shfl_xor(x, off, 64);
  return x;
}
__device__ inline u16 f2bf(float f) {   // RNE float->bf16 bits
  unsigned int u = __float_as_uint(f);
  unsigned int r = u + 0x7FFFu + ((u >> 16) & 1u);
  return (u16)(r >> 16);
}
__device__ inline float bf2f(u16 u) { return __uint_as_float(((unsigned int)u) << 16); }
__device__ inline float fexp2(float x) { return __builtin_amdgcn_exp2f(x); }
__device__ inline float frcp(float x) { return __builtin_amdgcn_rcpf(x); }

union bfrag { bf16x8 b; uint4 q; u16 u[8]; };

// async global->LDS, 16B per lane; lds base wave-uniform, HW scatters lane*16
__device__ inline void gload16(const u16* g, u16* l) {
  __builtin_amdgcn_global_load_lds(
      (const __attribute__((address_space(1))) void*)g,
      (__attribute__((address_space(3))) void*)l, 16, 0, 0);
}

// ---------------- weight transpose-convert: out[n][k] = bf16(in[k][n]) ------
__global__ __launch_bounds__(256)
void transpose_w(const float* __restrict__ in, u16* __restrict__ out,
                 int K, int N, size_t in_lstride, size_t out_lstride,
                 int row_off, int out_ld) {
  __shared__ float tile[32][33];
  int z = blockIdx.z;
  int kk0 = blockIdx.y * 32, nn0 = blockIdx.x * 32;
  int tx = threadIdx.x & 31, ty = threadIdx.x >> 5;
  const float* ip = in + z * in_lstride;
  u16* op = out + z * out_lstride;
#pragma unroll
  for (int i = 0; i < 4; i++)
    tile[ty + i * 8][tx] = ip[(size_t)(kk0 + ty + i * 8) * N + nn0 + tx];
  __syncthreads();
#pragma unroll
  for (int i = 0; i < 4; i++)
    op[(size_t)(row_off + nn0 + ty + i * 8) * out_ld + kk0 + tx] = f2bf(tile[tx][ty + i * 8]);
}

// ---------------- V transpose: vt[b*8+h][dk][key(1024 pad)] = v -------------
// grid (32, 2, 64), block 256
__global__ __launch_bounds__(256)
void vtrans_kernel(const u16* __restrict__ qkv, u16* __restrict__ vtg) {
  __shared__ u16 tile[32][33];
  int bh = blockIdx.z;
  int b = bh >> 3, hh = bh & 7;
  int k0 = blockIdx.x * 32;   // key
  int d0 = blockIdx.y * 32;   // dk
  int tx = threadIdx.x & 31, ty = threadIdx.x >> 5;
#pragma unroll
  for (int i = 0; i < 4; i++) {
    int key = k0 + ty + i * 8;
    u16 v = 0;
    if (key < L_) v = qkv[(size_t)(b * L_ + key) * QKVS + 1024 + hh * DK_ + d0 + tx];
    tile[ty + i * 8][tx] = v;
  }
  __syncthreads();
#pragma unroll
  for (int i = 0; i < 4; i++)
    vtg[((size_t)bh * DK_ + d0 + ty + i * 8) * 1024 + k0 + tx] = tile[tx][ty + i * 8];
}

// ---------------- qkv bias concat -------------------------------------------
__global__ __launch_bounds__(256)
void concat_bias(const float* __restrict__ bq, const float* __restrict__ bk,
                 const float* __restrict__ bv, float* __restrict__ bqkv) {
  int i = blockIdx.x * 256 + threadIdx.x;
  int l = i / QKVS, j = i % QKVS;
  float v = (j < 512) ? bq[l * 512 + j] : (j < 1024) ? bk[l * 512 + j - 512]
                                                     : bv[l * 512 + j - 1024];
  bqkv[i] = v;
}

// ---------------- embedding -------------------------------------------------
__global__ __launch_bounds__(512)
void embed_kernel(const float* __restrict__ x, const float* __restrict__ emb_w,
                  const float* __restrict__ emb_b, const float* __restrict__ pe,
                  float* __restrict__ h, u16* __restrict__ h16) {
  int bl = blockIdx.x;
  int l = bl % L_;
  int d = threadIdx.x;
  const float* xr = x + (size_t)bl * F_;
  float acc = emb_b[d] + pe[(size_t)l * DM_ + d];
#pragma unroll
  for (int f = 0; f < F_; f++) acc = fmaf(xr[f], emb_w[f * DM_ + d], acc);
  h[(size_t)bl * DM_ + d] = acc;
  h16[(size_t)bl * DM_ + d] = f2bf(acc);
}

// ---------------- bf16 MFMA GEMM (m97 structure) ----------------------------
// nscale: cols < nscale get *sval in epilogue (q pre-scale for attention)
template<int BN>
__global__ __launch_bounds__(256)
void gemm16(const u16* __restrict__ A, const u16* __restrict__ Bt,
            const float* __restrict__ bias, const float* __restrict__ resid,
            float* __restrict__ C32, u16* __restrict__ C16,
            int M, int K, int N, int relu, int nscale, float sval) {
  constexpr int NTW = BN / 32;
  constexpr int BJ  = BN / 64;
  __shared__ u16 As[128 * 32];
  __shared__ u16 Bs[BN * 32];
  int t = threadIdx.x;
  int w = t >> 6, lane = t & 63;
  int wr = w >> 1, wc = w & 1;
  int mloc = lane & 15, quad = lane >> 4;
  int m0 = blockIdx.y * 128, n0 = blockIdx.x * BN;

  const u16* agp[2]; u16* alds[2];
#pragma unroll
  for (int j = 0; j < 2; j++) {
    int r = w * 32 + j * 16 + (lane >> 2);
    int gm = m0 + r; if (gm > M - 1) gm = M - 1;
    int ch = (lane & 3) ^ ((r >> 1) & 3);
    agp[j] = A + (size_t)gm * K + ch * 8;
    alds[j] = As + (w * 32 + j * 16) * 32;
  }
  const u16* bgp[BJ]; u16* blds[BJ];
#pragma unroll
  for (int j = 0; j < BJ; j++) {
    int r = w * (16 * BJ) + j * 16 + (lane >> 2);
    int ch = (lane & 3) ^ ((r >> 1) & 3);
    bgp[j] = Bt + (size_t)(n0 + r) * K + ch * 8;
    blds[j] = Bs + (w * (16 * BJ) + j * 16) * 32;
  }
  const u16* apt[4];
#pragma unroll
  for (int mi = 0; mi < 4; mi++) {
    int tr = wr * 64 + mi * 16 + mloc;
    apt[mi] = As + tr * 32 + (quad ^ ((tr >> 1) & 3)) * 8;
  }
  const u16* bpt[NTW];
#pragma unroll
  for (int nt = 0; nt < NTW; nt++) {
    int tr = wc * (BN / 2) + nt * 16 + mloc;
    bpt[nt] = Bs + tr * 32 + (quad ^ ((tr >> 1) & 3)) * 8;
  }

  f32x4 acc[4][NTW];
#pragma unroll
  for (int mi = 0; mi < 4; mi++)
#pragma unroll
    for (int nt = 0; nt < NTW; nt++) acc[mi][nt] = (f32x4){0.f, 0.f, 0.f, 0.f};

  for (int k0 = 0; k0 < K; k0 += 32) {
    __syncthreads();
    gload16(agp[0] + k0, alds[0]);
    gload16(agp[1] + k0, alds[1]);
#pragma unroll
    for (int j = 0; j < BJ; j++) gload16(bgp[j] + k0, blds[j]);
    __syncthreads();
    bf16x8 af[4], bv[NTW];
#pragma unroll
    for (int mi = 0; mi < 4; mi++) af[mi] = *(const bf16x8*)apt[mi];
#pragma unroll
    for (int nt = 0; nt < NTW; nt++) bv[nt] = *(const bf16x8*)bpt[nt];
#pragma unroll
    for (int mi = 0; mi < 4; mi++)
#pragma unroll
      for (int nt = 0; nt < NTW; nt++)
        acc[mi][nt] = __builtin_amdgcn_mfma_f32_16x16x32_bf16(af[mi], bv[nt], acc[mi][nt], 0, 0, 0);
  }

#pragma unroll
  for (int mi = 0; mi < 4; mi++) {
#pragma unroll
    for (int r = 0; r < 4; r++) {
      int m = m0 + wr * 64 + mi * 16 + quad * 4 + r;
      if (m >= M) continue;
      size_t crow = (size_t)m * N;
#pragma unroll
      for (int nt = 0; nt < NTW; nt++) {
        int n = n0 + wc * (BN / 2) + nt * 16 + mloc;
        float vsum = acc[mi][nt][r] + bias[n];
        if (resid) vsum += resid[crow + n];
        if (n < nscale) vsum *= sval;
        if (relu) vsum = fmaxf(vsum, 0.f);
        if (C32) C32[crow + n] = vsum;
        if (C16) C16[crow + n] = f2bf(vsum);
      }
    }
  }
}

// ---------------- learned-mask projection (bf16 in/out, scaled) -------------
__global__ __launch_bounds__(128)
void lmproj_kernel(const u16* __restrict__ src, int col0, const float* __restrict__ w,
                   const float* __restrict__ bias, u16* __restrict__ dst,
                   float wscale, float bscale) {
  int bl = blockIdx.x;
  int t = threadIdx.x;
  int hh = t >> 4, p = t & 15;
  const u16* s = src + (size_t)bl * QKVS + col0 + hh * DK_;
  float acc = 0.f;
#pragma unroll
  for (int d = 0; d < DK_; d++) acc = fmaf(bf2f(s[d]), w[d * P_ + p], acc);
  dst[((size_t)bl * H_ + hh) * P_ + p] = f2bf(fmaf(acc, wscale, bias[p] * bscale));
}

// ---------------- MFMA flash attention, 128-key tiles, exp2-domain ----------
#define KT  128
#define LDQ 40    // Kp row stride
#define LDP 136   // Ps row stride
__global__ __launch_bounds__(256)
void attn_mfma_kernel(const u16* __restrict__ qkv, const u16* __restrict__ qpg,
                      const u16* __restrict__ kpg, const u16* __restrict__ vtg,
                      u16* __restrict__ ctx) {
  __shared__ u16 Ks[KT * 64];      // [key][dk], XOR-swizzled 8-elem chunks (8/row)
  __shared__ u16 Vt[64 * KT];      // [dk][key], XOR-swizzled (16/row)
  __shared__ u16 Kp[KT * LDQ];     // [key][p 0..31], 16..31 zero
  __shared__ u16 Ps[4 * 16 * LDP]; // per-wave P[16][128]

  int qt = blockIdx.x, bh = blockIdx.y;
  int b = bh >> 3, hh = bh & 7;
  int l0 = qt * 64;
  int t = threadIdx.x;
  int wv = t >> 6, lane = t & 63;
  int m = lane & 15, quad = lane >> 4;

  // Q (pre-scaled by 0.125*log2e in GEMM) + qp (pre-scaled by 2*log2e)
  int lq = l0 + wv * 16 + m; if (lq > L_ - 1) lq = L_ - 1;
  const u16* qrow = qkv + (size_t)(b * L_ + lq) * QKVS + hh * DK_;
  bf16x8 qa0 = *(const bf16x8*)(qrow + quad * 8);
  bf16x8 qa1 = *(const bf16x8*)(qrow + 32 + quad * 8);
  bfrag qpa;
  if (quad < 2) {
    const u16* qprow = qpg + ((size_t)(b * L_ + lq) * H_ + hh) * P_;
    qpa.q = *(const uint4*)(qprow + quad * 8);
  } else {
    qpa.q = make_uint4(0u, 0u, 0u, 0u);
  }

  // staging address precompute
  // Ks: lane covers row (t>>3) of 32-row group j, chunk slot t&7, global chunk XOR'd
  const u16* ks_g = qkv + ((size_t)b * L_ + (t >> 3)) * QKVS + 512 + hh * DK_
                    + ((t & 7) ^ ((t >> 3) & 7)) * 8;
  u16* ks_l = Ks + (t >> 6) * 512;   // + j*2048 per group
  const u16* vt_g = vtg + ((size_t)bh * DK_ + (t >> 4)) * 1024
                    + (((t & 15) ^ (t >> 4)) * 8);
  u16* vt_l = Vt + (t >> 6) * 512;

  f32x4 O[4];
#pragma unroll
  for (int nt = 0; nt < 4; nt++) O[nt] = (f32x4){0.f, 0.f, 0.f, 0.f};
  float mrun[4] = {-3e38f, -3e38f, -3e38f, -3e38f};
  float lrun[4] = {0.f, 0.f, 0.f, 0.f};

  for (int s0 = 0; s0 < L_; s0 += KT) {
    // kp tile loads to VGPR (rows beyond L_ read in-ws garbage; masked later)
    uint4 p0, p1;
    if (t < KT) {
      const u16* pr = kpg + ((size_t)(b * L_ + s0 + t) * H_ + hh) * P_;
      p0 = *(const uint4*)(pr);
      p1 = *(const uint4*)(pr + 8);
    }
    __syncthreads();   // all waves done reading previous tile
#pragma unroll
    for (int j = 0; j < 4; j++) {
      gload16(ks_g + ((size_t)s0 + j * 32) * QKVS, ks_l + j * 2048);
      gload16(vt_g + s0 + (size_t)j * 16 * 1024, vt_l + j * 2048);
    }
    if (t < KT) {
      *(uint4*)&Kp[t * LDQ]      = p0;
      *(uint4*)&Kp[t * LDQ + 8]  = p1;
      *(uint4*)&Kp[t * LDQ + 16] = make_uint4(0u, 0u, 0u, 0u);
      *(uint4*)&Kp[t * LDQ + 24] = make_uint4(0u, 0u, 0u, 0u);
    }
    __syncthreads();   // vmcnt(0) drain: tile staged

    // scores: sacc = log2e/8 * qk (Q pre-scaled); tanh bias in log2 domain
    float scp[8][4];
    const f32x4 zz = (f32x4){0.f, 0.f, 0.f, 0.f};
#pragma unroll
    for (int nt = 0; nt < 8; nt++) {
      const u16* kb = Ks + (nt * 16 + m) * 64;
      int x0 = ((quad) ^ (m & 7)) * 8;        // kc=0 chunk
      int x1 = ((4 + quad) ^ (m & 7)) * 8;    // kc=1 chunk
      f32x4 sacc = __builtin_amdgcn_mfma_f32_16x16x32_bf16(qa0, *(const bf16x8*)(kb + x0), zz, 0, 0, 0);
      sacc = __builtin_amdgcn_mfma_f32_16x16x32_bf16(qa1, *(const bf16x8*)(kb + x1), sacc, 0, 0, 0);
      f32x4 macc = __builtin_amdgcn_mfma_f32_16x16x32_bf16(
          qpa.b, *(const bf16x8*)(Kp + (nt * 16 + m) * LDQ + quad * 8), zz, 0, 0, 0);
#pragma unroll
      for (int r = 0; r < 4; r++) {
        // macc = 2*log2e*x -> e=exp(2x); tanh_l2 = log2e - 2*log2e/(e+1)
        float e = fexp2(macc[r]);
        float d = frcp(e + 1.f);
        float th = fmaf(d, -2.f * L2E_, L2E_);
        scp[nt][r] = sacc[r] + th;
      }
    }
    if (s0 + KT > L_) {   // tail masking (last tile only)
#pragma unroll
      for (int nt = 0; nt < 8; nt++) {
        if (s0 + nt * 16 + m >= L_) {
#pragma unroll
          for (int r = 0; r < 4; r++) scp[nt][r] = -3e38f;
        }
      }
    }

    // online softmax in exp2 domain
    float mnew[4], alpha[4];
#pragma unroll
    for (int r = 0; r < 4; r++) {
      float rm = scp[0][r];
#pragma unroll
      for (int nt = 1; nt < 8; nt++) rm = fmaxf(rm, scp[nt][r]);
#pragma unroll
      for (int msk = 1; msk < 16; msk <<= 1) rm = fmaxf(rm, __shfl_xor(rm, msk, 64));
      mnew[r] = fmaxf(mrun[r], rm);
      alpha[r] = fexp2(mrun[r] - mnew[r]);
      mrun[r] = mnew[r];
    }
    float rs[4] = {0.f, 0.f, 0.f, 0.f};
#pragma unroll
    for (int nt = 0; nt < 8; nt++)
#pragma unroll
      for (int r = 0; r < 4; r++) {
        float p = fexp2(scp[nt][r] - mnew[r]);
        scp[nt][r] = p;
        rs[r] += p;
      }
#pragma unroll
    for (int r = 0; r < 4; r++) {
#pragma unroll
      for (int msk = 1; msk < 16; msk <<= 1) rs[r] += __shfl_xor(rs[r], msk, 64);
      lrun[r] = lrun[r] * alpha[r] + rs[r];
    }
    f32x4 av = (f32x4){alpha[0], alpha[1], alpha[2], alpha[3]};
#pragma unroll
    for (int nt = 0; nt < 4; nt++) O[nt] *= av;

    // P: C-layout -> per-wave LDS -> A-layout
    u16* pw = Ps + wv * (16 * LDP);
#pragma unroll
    for (int nt = 0; nt < 8; nt++)
#pragma unroll
      for (int r = 0; r < 4; r++)
        pw[(quad * 4 + r) * LDP + nt * 16 + m] = f2bf(scp[nt][r]);

#pragma unroll
    for (int kc = 0; kc < 4; kc++) {
      bf16x8 pa = *(const bf16x8*)(pw + m * LDP + kc * 32 + quad * 8);
#pragma unroll
      for (int nt = 0; nt < 4; nt++) {
        const u16* vb = Vt + (nt * 16 + m) * KT + (((kc * 4 + quad) ^ m) * 8);
        O[nt] = __builtin_amdgcn_mfma_f32_16x16x32_bf16(pa, *(const bf16x8*)vb, O[nt], 0, 0, 0);
      }
    }
  }

  float inv[4];
#pragma unroll
  for (int r = 0; r < 4; r++) inv[r] = frcp(lrun[r]);
#pragma unroll
  for (int r = 0; r < 4; r++) {
    int l = l0 + wv * 16 + quad * 4 + r;
    if (l >= L_) continue;
    u16* crow = ctx + ((size_t)(b * L_ + l)) * DM_ + hh * DK_;
#pragma unroll
    for (int nt = 0; nt < 4; nt++) crow[nt * 16 + m] = f2bf(O[nt][r] * inv[r]);
  }
}

// ---------------- layernorm -------------------------------------------------
__global__ __launch_bounds__(256)
void ln_kernel(const float* __restrict__ a, const float* __restrict__ badd,
               const float* __restrict__ g, const float* __restrict__ be,
               float* __restrict__ o, u16* __restrict__ o16) {
  int row = blockIdx.x;
  int t = threadIdx.x;
  size_t base = (size_t)row * DM_;
  float x0 = a[base + t], x1 = a[base + t + 256];
  if (badd) { x0 += badd[base + t]; x1 += badd[base + t + 256]; }
  float s = wave_reduce_sum(x0 + x1);
  float ss = wave_reduce_sum(x0 * x0 + x1 * x1);
  __shared__ float sh_s[4], sh_ss[4];
  int wv = t >> 6, lane = t & 63;
  if (lane == 0) { sh_s[wv] = s; sh_ss[wv] = ss; }
  __syncthreads();
  float S = sh_s[0] + sh_s[1] + sh_s[2] + sh_s[3];
  float SS = sh_ss[0] + sh_ss[1] + sh_ss[2] + sh_ss[3];
  float mean = S * (1.0f / DM_);
  float var = SS * (1.0f / DM_) - mean * mean;
  float rstd = rsqrtf(var + EPS_);
  float r0 = (x0 - mean) * rstd * g[t] + be[t];
  float r1 = (x1 - mean) * rstd * g[t + 256] + be[t + 256];
  o[base + t] = r0; o[base + t + 256] = r1;
  if (o16) { o16[base + t] = f2bf(r0); o16[base + t + 256] = f2bf(r1); }
}

// ---------------- fused double layernorm ------------------------------------
__global__ __launch_bounds__(256)
void ln2x_kernel(const float* __restrict__ hin, const float* __restrict__ y,
                 const float* __restrict__ g, const float* __restrict__ be,
                 float* __restrict__ o32, u16* __restrict__ o16) {
  int row = blockIdx.x;
  int t = threadIdx.x;
  size_t base = (size_t)row * DM_;
  float y0 = y[base + t], y1 = y[base + t + 256];
  float x0 = hin[base + t] + y0, x1 = hin[base + t + 256] + y1;
  __shared__ float sh_s[4], sh_ss[4];
  int wv = t >> 6, lane = t & 63;
  float g0 = g[t], g1v = g[t + 256], b0 = be[t], b1v = be[t + 256];

  float s = wave_reduce_sum(x0 + x1);
  float ss = wave_reduce_sum(x0 * x0 + x1 * x1);
  if (lane == 0) { sh_s[wv] = s; sh_ss[wv] = ss; }
  __syncthreads();
  float S = sh_s[0] + sh_s[1] + sh_s[2] + sh_s[3];
  float SS = sh_ss[0] + sh_ss[1] + sh_ss[2] + sh_ss[3];
  float mean = S * (1.0f / DM_);
  float var = SS * (1.0f / DM_) - mean * mean;
  float rstd = rsqrtf(var + EPS_);
  float h20 = (x0 - mean) * rstd * g0 + b0 + y0;
  float h21 = (x1 - mean) * rstd * g1v + b1v + y1;
  __syncthreads();

  s = wave_reduce_sum(h20 + h21);
  ss = wave_reduce_sum(h20 * h20 + h21 * h21);
  if (lane == 0) { sh_s[wv] = s; sh_ss[wv] = ss; }
  __syncthreads();
  S = sh_s[0] + sh_s[1] + sh_s[2] + sh_s[3];
  SS = sh_ss[0] + sh_ss[1] + sh_ss[2] + sh_ss[3];
  mean = S * (1.0f / DM_);
  var = SS * (1.0f / DM_) - mean * mean;
  rstd = rsqrtf(var + EPS_);
  float r0 = (h20 - mean) * rstd * g0 + b0;
  float r1 = (h21 - mean) * rstd * g1v + b1v;
  o32[base + t] = r0; o32[base + t + 256] = r1;
  if (o16) { o16[base + t] = f2bf(r0); o16[base + t + 256] = f2bf(r1); }
}

// ---------------- final head ------------------------------------------------
__global__ __launch_bounds__(512)
void final_kernel(const float* __restrict__ h, const float* __restrict__ gn,
                  const float* __restrict__ bn, const float* __restrict__ fcw,
                  const float* __restrict__ fcb, float* __restrict__ out) {
  int b = blockIdx.x;
  int t = threadIdx.x;
  size_t base = ((size_t)b * L_ + (L_ - 1)) * DM_;
  float x = h[base + t];
  float s = wave_reduce_sum(x);
  float ss = wave_reduce_sum(x * x);
  __shared__ float sh_s[8], sh_ss[8];
  int wv = t >> 6, lane = t & 63;
  if (lane == 0) { sh_s[wv] = s; sh_ss[wv] = ss; }
  __syncthreads();
  float S = 0.f, SS = 0.f;
#pragma unroll
  for (int i = 0; i < 8; i++) { S += sh_s[i]; SS += sh_ss[i]; }
  float mean = S * (1.0f / DM_);
  float var = SS * (1.0f / DM_) - mean * mean;
  float rstd = rsqrtf(var + EPS_);
  __shared__ float hn[DM_];
  hn[t] = (x - mean) * rstd * gn[t] + bn[t];
  __syncthreads();
  if (t < PRED_) {
    float acc = fcb[t];
#pragma unroll 8
    for (int d = 0; d < DM_; d++) acc = fmaf(hn[d], fcw[d * PRED_ + t], acc);
    out[b * PRED_ + t] = acc;
  }
}

// ---------------- driver ----------------
extern "C" void kernel_launch(void* const* d_in, const int* in_sizes, int n_in,
                              void* d_out, int out_size, void* d_ws, size_t ws_size,
                              hipStream_t stream) {
  const float* x     = (const float*)d_in[0];
  const float* emb_w = (const float*)d_in[1];
  const float* emb_b = (const float*)d_in[2];
  const float* pe    = (const float*)d_in[3];
  const float* Wq = (const float*)d_in[4];  const float* bq = (const float*)d_in[5];
  const float* Wk = (const float*)d_in[6];  const float* bk = (const float*)d_in[7];
  const float* Wv = (const float*)d_in[8];  const float* bv = (const float*)d_in[9];
  const float* Wo = (const float*)d_in[10]; const float* bo = (const float*)d_in[11];
  const float* W1 = (const float*)d_in[12]; const float* b1 = (const float*)d_in[13];
  const float* W2 = (const float*)d_in[14]; const float* b2 = (const float*)d_in[15];
  const float* g1 = (const float*)d_in[16]; const float* be1 = (const float*)d_in[17];
  const float* g2 = (const float*)d_in[18]; const float* be2 = (const float*)d_in[19];
  const float* lm_qw = (const float*)d_in[20]; const float* lm_qb = (const float*)d_in[21];
  const float* lm_kw = (const float*)d_in[22]; const float* lm_kb = (const float*)d_in[23];
  const float* gn = (const float*)d_in[24]; const float* bn = (const float*)d_in[25];
  const float* fc_w = (const float*)d_in[26]; const float* fc_b = (const float*)d_in[27];
  float* out = (float*)d_out;

  const size_t ROWS = (size_t)B_ * L_;     // 8000
  u16* qkv16 = (u16*)d_ws;                               // [8000][1536]
  u16* ctx16 = qkv16 + ROWS * QKVS;                      // [8000][512]
  u16* ffn1  = qkv16;                                    // [8000][2048] alias
  u16* h16   = ctx16 + ROWS * DM_;                       // [8000][512]
  u16* qp16  = h16 + ROWS * DM_;                         // [8000][128]
  u16* kp16  = qp16 + ROWS * H_ * P_;
  u16* Wqkv_t = kp16 + ROWS * H_ * P_;                   // [NL][1536][512]
  u16* Wo_t   = Wqkv_t + (size_t)NL_ * QKVS * DM_;       // [NL][512][512]
  u16* W1_t   = Wo_t + (size_t)NL_ * DM_ * DM_;          // [NL][2048][512]
  u16* W2_t   = W1_t + (size_t)NL_ * DFF_ * DM_;         // [NL][512][2048]
  float* h32  = (float*)(W2_t + (size_t)NL_ * DM_ * DFF_);
  float* t0   = h32 + ROWS * DM_;
  float* bqkv = t0 + ROWS * DM_;                         // [NL][1536]
  u16* vtg    = (u16*)t0;   // [64][64][1024] = 8.4 MB, aliases t0 (dead during attn)

  transpose_w<<<dim3(16, 16, NL_), 256, 0, stream>>>(Wq, Wqkv_t, DM_, DM_, (size_t)DM_ * DM_, (size_t)QKVS * DM_, 0, DM_);
  transpose_w<<<dim3(16, 16, NL_), 256, 0, stream>>>(Wk, Wqkv_t, DM_, DM_, (size_t)DM_ * DM_, (size_t)QKVS * DM_, 512, DM_);
  transpose_w<<<dim3(16, 16, NL_), 256, 0, stream>>>(Wv, Wqkv_t, DM_, DM_, (size_t)DM_ * DM_, (size_t)QKVS * DM_, 1024, DM_);
  transpose_w<<<dim3(16, 16, NL_), 256, 0, stream>>>(Wo, Wo_t, DM_, DM_, (size_t)DM_ * DM_, (size_t)DM_ * DM_, 0, DM_);
  transpose_w<<<dim3(64, 16, NL_), 256, 0, stream>>>(W1, W1_t, DM_, DFF_, (size_t)DM_ * DFF_, (size_t)DFF_ * DM_, 0, DM_);
  transpose_w<<<dim3(16, 64, NL_), 256, 0, stream>>>(W2, W2_t, DFF_, DM_, (size_t)DFF_ * DM_, (size_t)DM_ * DFF_, 0, DFF_);
  concat_bias<<<NL_ * QKVS / 256, 256, 0, stream>>>(bq, bk, bv, bqkv);

  embed_kernel<<<dim3((unsigned)ROWS), 512, 0, stream>>>(x, emb_w, emb_b, pe, h32, h16);

  dim3 g_qkv(QKVS / 128, 63);
  dim3 g_ffn1(DFF_ / 128, 63);
  dim3 g_n512(DM_ / 64, 63);
  dim3 g_attn(16, B_ * H_);

  for (int i = 0; i < NL_; i++) {
    gemm16<128><<<g_qkv, 256, 0, stream>>>(h16, Wqkv_t + (size_t)i * QKVS * DM_,
        bqkv + i * QKVS, nullptr, nullptr, qkv16, 8000, DM_, QKVS, 0, 512, C_QS);

    lmproj_kernel<<<dim3((unsigned)ROWS), 128, 0, stream>>>(qkv16, 0, lm_qw, lm_qb, qp16, WS_QP, BS_QP);
    lmproj_kernel<<<dim3((unsigned)ROWS), 128, 0, stream>>>(qkv16, 512, lm_kw, lm_kb, kp16, 1.0f, 1.0f);
    vtrans_kernel<<<dim3(32, 2, B_ * H_), 256, 0, stream>>>(qkv16, vtg);

    attn_mfma_kernel<<<g_attn, 256, 0, stream>>>(qkv16, qp16, kp16, vtg, ctx16);

    gemm16<64><<<g_n512, 256, 0, stream>>>(ctx16, Wo_t + (size_t)i * DM_ * DM_,
        bo + i * DM_, h32, t0, nullptr, 8000, DM_, DM_, 0, 0, 1.0f);
    ln_kernel<<<dim3((unsigned)ROWS), 256, 0, stream>>>(t0, nullptr, g1 + i * DM_, be1 + i * DM_, h32, h16);

    gemm16<128><<<g_ffn1, 256, 0, stream>>>(h16, W1_t + (size_t)i * DFF_ * DM_,
        b1 + i * DFF_, nullptr, nullptr, ffn1, 8000, DM_, DFF_, 1, 0, 1.0f);
    gemm16<64><<<g_n512, 256, 0, stream>>>(ffn1, W2_t + (size_t)i * DM_ * DFF_,
        b2 + i * DM_, nullptr, t0, nullptr, 8000, DFF_, DM_, 0, 0, 1.0f);

    ln2x_kernel<<<dim3((unsigned)ROWS), 256, 0, stream>>>(h32, t0, g2 + i * DM_, be2 + i * DM_, h32, h16);
  }

  final_kernel<<<B_, 512, 0, stream>>>(h32, gn, bn, fc_w, fc_b, out);
}